// Round 9
// baseline (1235.556 us; speedup 1.0000x reference)
//
#include <hip/hip_runtime.h>
#include <hip/hip_bf16.h>
#include <math.h>

#define A_   12
#define H_   6
#define N_   96
#define T_   80
#define G_   640
#define E_   132
#define E2_  144
#define ROWS_ 7680

typedef const __hip_bfloat16* bfp;
typedef __hip_bfloat16 bf16;
typedef __attribute__((ext_vector_type(8))) short short8;
typedef __attribute__((ext_vector_type(4))) short short4v;
typedef __attribute__((ext_vector_type(4))) float f32x4;

// ---- bf16 weight arena element offsets (in bf16 units) ----
#define WB_QKV   0                /* [3][576][192]  */
#define WB_OUT   331776           /* [3][192][192]  */
#define WB_FW1   442368           /* [3][768][192]  */
#define WB_FW2   884736           /* [3][192][768]  */
#define WB_GAT   1327104          /* [3][2304][192] (gwl|gwr) */
#define WB_W1    2654208          /* [16][64] BN-folded */
#define WB_W2    2655232          /* [64][256] BN-folded */
#define WB_W3T   2671616          /* [192][256] BN-folded, transposed */
#define WB_GWE   2720768          /* [3][2304] */
#define WB_GATT  2727680          /* [3][1152] */
#define WB_TOT   2731136
// ---- f32 bias arena element offsets ----
#define BB_QKV   0                /* [3][576] */
#define BB_OUT   1728             /* [3][192] */
#define BB_FW1   2304             /* [3][768] */
#define BB_FW2   4608             /* [3][192] */
#define BB_GAT   5184             /* [3][2304] */
#define BB_B1    12096            /* [64]  folded */
#define BB_B2    12160            /* [256] folded */
#define BB_B3    12416            /* [192] folded */
#define BB_TOT   12608

__device__ __forceinline__ float b2f(bf16 x){ return __bfloat162float(x); }
__device__ __forceinline__ float s2f(short x){ return __uint_as_float(((unsigned)(unsigned short)x)<<16); }
__device__ __forceinline__ float ldf(const void* p, size_t i, int f){
    return f ? __bfloat162float(((const bf16*)p)[i]) : ((const float*)p)[i];
}

// dtype probe: even uint16s of f32 storage are random mantissa halves.
__global__ void k_detect(const void* sf, int* flag)
{
    const unsigned short* u = (const unsigned short*)sf;
    int sane = 0;
    for (int i = 0; i < 64; i++){
        unsigned short v = u[2*i];
        int e = (v >> 7) & 0xFF;
        if (e == 0 || (e >= 100 && e <= 140)) sane++;
    }
    *flag = (sane >= 48) ? 1 : 0;
}

// ---- convert+transpose all weights into bf16 arena; biases (BN-folded) into f32 arena ----
__global__ __launch_bounds__(256) void k_convert(
    const void* qkvw, const void* outw, const void* fw1, const void* fw2,
    const void* gwl, const void* gwr, const void* gwe, const void* gatt,
    const void* W1, const void* b1, const void* g1, const void* be1, const void* m1, const void* v1,
    const void* W2, const void* b2, const void* g2, const void* be2, const void* m2, const void* v2,
    const void* W3, const void* b3, const void* g3, const void* be3, const void* m3, const void* v3,
    const void* qkvb, const void* outb, const void* fb1, const void* fb2,
    const void* gbl, const void* gbr,
    const int* flagp, bf16* WB, float* BB)
{
    const int f = *flagp;
    size_t idx = (size_t)blockIdx.x*256 + threadIdx.x;
    if (idx < WB_TOT){
        float v;
        if (idx < WB_OUT){            size_t i=idx-WB_QKV; int l=i/110592; int r=i%110592; int n=r/192, k=r%192;
            v = ldf(qkvw, (size_t)l*110592 + (size_t)k*576 + n, f);
        } else if (idx < WB_FW1){     size_t i=idx-WB_OUT; int l=i/36864; int r=i%36864; int n=r/192, k=r%192;
            v = ldf(outw, (size_t)l*36864 + (size_t)k*192 + n, f);
        } else if (idx < WB_FW2){     size_t i=idx-WB_FW1; int l=i/147456; int r=i%147456; int n=r/192, k=r%192;
            v = ldf(fw1, (size_t)l*147456 + (size_t)k*768 + n, f);
        } else if (idx < WB_GAT){     size_t i=idx-WB_FW2; int l=i/147456; int r=i%147456; int n=r/768, k=r%768;
            v = ldf(fw2, (size_t)l*147456 + (size_t)k*192 + n, f);
        } else if (idx < WB_W1){      size_t i=idx-WB_GAT; int l=i/442368; int r=i%442368; int n=r/192, k=r%192;
            if (n < 1152) v = ldf(gwl, (size_t)l*221184 + (size_t)k*1152 + n, f);
            else          v = ldf(gwr, (size_t)l*221184 + (size_t)k*1152 + (n-1152), f);
        } else if (idx < WB_W2){      size_t i=idx-WB_W1; int o=i%64;
            float s = ldf(g1,o,f)*rsqrtf(ldf(v1,o,f)+1e-5f);
            v = ldf(W1, i, f) * s;
        } else if (idx < WB_W3T){     size_t i=idx-WB_W2; int o=i%256;
            float s = ldf(g2,o,f)*rsqrtf(ldf(v2,o,f)+1e-5f);
            v = ldf(W2, i, f) * s;
        } else if (idx < WB_GWE){     size_t i=idx-WB_W3T; int n=i/256, k=i%256;
            float s = ldf(g3,n,f)*rsqrtf(ldf(v3,n,f)+1e-5f);
            v = ldf(W3, (size_t)k*192 + n, f) * s;
        } else if (idx < WB_GATT){    size_t i=idx-WB_GWE;
            v = ldf(gwe, i, f);
        } else {                      size_t i=idx-WB_GATT;
            v = ldf(gatt, i, f);
        }
        WB[idx] = __float2bfloat16(v);
    } else if (idx < WB_TOT + BB_TOT){
        size_t j = idx - WB_TOT;
        float v;
        if (j < BB_OUT)        v = ldf(qkvb, j, f);
        else if (j < BB_FW1)   v = ldf(outb, j-BB_OUT, f);
        else if (j < BB_FW2)   v = ldf(fb1, j-BB_FW1, f);
        else if (j < BB_GAT)   v = ldf(fb2, j-BB_FW2, f);
        else if (j < BB_B1){   size_t i=j-BB_GAT; int l=i/2304; int o=i%2304;
            v = (o<1152) ? ldf(gbl, (size_t)l*1152+o, f) : ldf(gbr, (size_t)l*1152+o-1152, f);
        } else if (j < BB_B2){ int o=j-BB_B1;
            float s = ldf(g1,o,f)*rsqrtf(ldf(v1,o,f)+1e-5f);
            v = (ldf(b1,o,f)-ldf(m1,o,f))*s + ldf(be1,o,f);
        } else if (j < BB_B3){ int o=j-BB_B2;
            float s = ldf(g2,o,f)*rsqrtf(ldf(v2,o,f)+1e-5f);
            v = (ldf(b2,o,f)-ldf(m2,o,f))*s + ldf(be2,o,f);
        } else {               int o=j-BB_B3;
            float s = ldf(g3,o,f)*rsqrtf(ldf(v3,o,f)+1e-5f);
            v = (ldf(b3,o,f)-ldf(m3,o,f))*s + ldf(be3,o,f);
        }
        BB[j] = v;
    }
}

// ---- MLP stages 1+2: in16 -> 64 -> 256 (relu, BN folded), 16 rows/block ----
__global__ __launch_bounds__(256) void k_mlp_a(
    const void* sf, const int* ids, const void* emb, const int* flagp,
    const bf16* __restrict__ WB, const float* __restrict__ BB, bf16* h2g)
{
    __shared__ float in16[16][16];
    __shared__ float h1[16][64];
    const int f = *flagp;
    int tid = threadIdx.x;
    int row0 = blockIdx.x * 16;
    {
        int r = tid >> 4, i = tid & 15;
        int row = row0 + r;
        float v;
        if (i < 4) v = ldf(sf, (size_t)row*4 + i, f);
        else {
            int id = ids[row / T_]; if (id < 0) id = 0; if (id > 599) id = 599;
            v = ldf(emb, (size_t)id*12 + (i-4), f);
        }
        in16[r][i] = v;
    }
    __syncthreads();
    {
        int o = tid & 63, rg = tid >> 6;
        float acc[4];
        float bv = BB[BB_B1 + o];
        #pragma unroll
        for (int j=0;j<4;j++) acc[j] = bv;
        for (int i=0;i<16;i++){
            float w = b2f(WB[WB_W1 + i*64 + o]);
            #pragma unroll
            for (int j=0;j<4;j++) acc[j] += in16[rg*4+j][i]*w;
        }
        #pragma unroll
        for (int j=0;j<4;j++) h1[rg*4+j][o] = acc[j] > 0.f ? acc[j] : 0.f;
    }
    __syncthreads();
    {
        int o = tid;
        float acc[16];
        float bv = BB[BB_B2 + o];
        #pragma unroll
        for (int r=0;r<16;r++) acc[r] = bv;
        for (int i=0;i<64;i++){
            float w = b2f(WB[WB_W2 + i*256 + o]);
            #pragma unroll
            for (int r=0;r<16;r++) acc[r] += h1[r][i]*w;
        }
        for (int r=0;r<16;r++){
            float v = acc[r] > 0.f ? acc[r] : 0.f;
            h2g[(size_t)(row0+r)*256 + o] = __float2bfloat16(v);
        }
    }
}

// ---- MFMA GEMM: C[rows x N] = A[rows x K](bf16) @ Wt[N x K]^T + bias ----
// mode 0: bf16 store | 1: GELU bf16 | 2: outf = res + v | 3: relu -> out0(flag dtype) & xf = relu + PE
__global__ __launch_bounds__(256) void k_mgemm(
    const bf16* __restrict__ A, const bf16* __restrict__ Wt, const float* __restrict__ bias,
    bf16* outh, float* outf, const float* __restrict__ res, void* out0, const int* flagp,
    int K, int N, int mode)
{
    __shared__ short As[64*200];
    __shared__ short Bs[64*200];
    int tid = threadIdx.x;
    int w = tid >> 6, lane = tid & 63, q = lane >> 4, li = lane & 15;
    int m0 = blockIdx.x * 64, n0 = blockIdx.y * 64;
    const int f = flagp ? *flagp : 0;
    f32x4 acc[4];
    #pragma unroll
    for (int nt=0;nt<4;nt++) acc[nt] = (f32x4){0.f,0.f,0.f,0.f};
    int nkc = (K + 191) / 192;
    for (int kc = 0; kc < nkc; kc++){
        int kcw = K - kc*192; if (kcw > 192) kcw = 192;
        int vr = kcw >> 3;
        const bf16* Ab = A  + (size_t)m0*K + kc*192;
        const bf16* Bb = Wt + (size_t)n0*K + kc*192;
        for (int idx = tid; idx < 64*vr; idx += 256){
            int r = idx / vr, kv = idx - r*vr;
            *(short8*)&As[r*200 + kv*8] = *(const short8*)&Ab[(size_t)r*K + kv*8];
        }
        for (int idx = tid; idx < 64*vr; idx += 256){
            int r = idx / vr, kv = idx - r*vr;
            *(short8*)&Bs[r*200 + kv*8] = *(const short8*)&Bb[(size_t)r*K + kv*8];
        }
        __syncthreads();
        int kkn = kcw >> 5;
        for (int kk = 0; kk < kkn; kk++){
            int ko = kk*32 + q*8;
            short8 a = *(short8*)&As[(w*16+li)*200 + ko];
            #pragma unroll
            for (int nt = 0; nt < 4; nt++){
                short8 b = *(short8*)&Bs[(nt*16+li)*200 + ko];
                acc[nt] = __builtin_amdgcn_mfma_f32_16x16x32_bf16(a, b, acc[nt], 0, 0, 0);
            }
        }
        __syncthreads();
    }
    int rb = m0 + w*16 + q*4;
    #pragma unroll
    for (int nt = 0; nt < 4; nt++){
        int col = n0 + nt*16 + li;
        float bv = bias[col];
        #pragma unroll
        for (int p = 0; p < 4; p++){
            int row = rb + p;
            float v = acc[nt][p] + bv;
            size_t idx = (size_t)row*N + col;
            if (mode == 0) outh[idx] = __float2bfloat16(v);
            else if (mode == 1) outh[idx] = __float2bfloat16(0.5f*v*(1.f + erff(v*0.70710678118654752f)));
            else if (mode == 2) outf[idx] = v + res[idx];
            else {
                float r2 = v > 0.f ? v : 0.f;
                if (f) ((bf16*)out0)[idx] = __float2bfloat16(r2);
                else   ((float*)out0)[idx] = r2;
                int t = row % T_;
                int i2 = col & ~1;
                float dv = expf((float)i2 * (-9.210340371976184f/192.f));
                float ang = (float)t * dv;
                outf[idx] = r2 + ((col & 1) ? cosf(ang) : sinf(ang));
            }
        }
    }
}

// ---- LayerNorm (one wave per row), optional permute to node order ----
__global__ __launch_bounds__(256) void k_ln(const float* __restrict__ x, const void* g, const void* b,
                     size_t gOff, const int* flagp, bf16* out, int permute)
{
    const int f = *flagp;
    int tid = threadIdx.x;
    int row = blockIdx.x*4 + (tid>>6);
    int lane = tid & 63;
    const float* xr = x + (size_t)row*192;
    float v0 = xr[lane], v1 = xr[lane+64], v2 = xr[lane+128];
    float s = v0+v1+v2;
    float qq = v0*v0+v1*v1+v2*v2;
    #pragma unroll
    for (int off=32; off; off>>=1){ s += __shfl_xor(s, off); qq += __shfl_xor(qq, off); }
    float mean = s * (1.f/192.f);
    float var  = qq * (1.f/192.f) - mean*mean;
    float rs = rsqrtf(var + 1e-5f);
    int orow = row;
    if (permute){ int n = row/T_, t = row%T_; int bb = n/A_, a = n%A_; orow = (bb*T_+t)*A_ + a; }
    bf16* op = out + (size_t)orow*192;
    op[lane]     = __float2bfloat16((v0-mean)*rs*ldf(g,gOff+lane,f)     + ldf(b,gOff+lane,f));
    op[lane+64]  = __float2bfloat16((v1-mean)*rs*ldf(g,gOff+lane+64,f)  + ldf(b,gOff+lane+64,f));
    op[lane+128] = __float2bfloat16((v2-mean)*rs*ldf(g,gOff+lane+128,f) + ldf(b,gOff+lane+128,f));
}

// ---- causal attention, one wave per (seq, head, 16-query tile); online softmax ----
__global__ __launch_bounds__(64) void k_attn(bfp qkv, bf16* attn_o)
{
    __shared__ float Ks[80][32];
    __shared__ float Vs[80][32];
    int bid = blockIdx.x;
    int qt = bid % 5;
    int nh = bid / 5;
    int n = nh / H_, h = nh % H_;
    int tid = threadIdx.x;
    for (int idx = tid; idx < 640; idx += 64){
        int r = idx >> 3, c4 = (idx & 7) << 2;
        const bf16* rp = qkv + (size_t)(n*T_+r)*576 + h*32 + c4;
        short4v kv = *(const short4v*)(rp + 192);
        short4v vv = *(const short4v*)(rp + 384);
        f32x4 kf, vf;
        #pragma unroll
        for (int e=0;e<4;e++){
            kf[e] = __uint_as_float(((unsigned)(unsigned short)kv[e])<<16);
            vf[e] = __uint_as_float(((unsigned)(unsigned short)vv[e])<<16);
        }
        *(f32x4*)&Ks[r][c4] = kf;
        *(f32x4*)&Vs[r][c4] = vf;
    }
    __syncthreads();
    int qi = tid & 15, p = tid >> 4;
    int q = qt*16 + qi;
    float qv[8];
    const bf16* qp = qkv + (size_t)(n*T_+q)*576 + h*32 + p*8;
    #pragma unroll
    for (int c=0;c<8;c++) qv[c] = b2f(qp[c]);
    float m = -1e30f, l = 0.f;
    float acc[8];
    #pragma unroll
    for (int c=0;c<8;c++) acc[c]=0.f;
    int jmax = qt*16 + 15;
    for (int j = 0; j <= jmax; j++){
        float s = 0.f;
        #pragma unroll
        for (int c=0;c<8;c++) s += qv[c]*Ks[j][p*8+c];
        s += __shfl_xor(s, 16);
        s += __shfl_xor(s, 32);
        s *= 0.17677669529663687f;
        if (j > q) s = -1e30f;
        float mn = fmaxf(m, s);
        float corr = expf(m - mn);
        float e = expf(s - mn);
        l = l*corr + e;
        #pragma unroll
        for (int c=0;c<8;c++) acc[c] = acc[c]*corr + e*Vs[j][p*8+c];
        m = mn;
    }
    float inv = 1.f/l;
    bf16* op = attn_o + (size_t)(n*T_+q)*192 + h*32 + p*8;
    #pragma unroll
    for (int c=0;c<8;c++) op[c] = __float2bfloat16(acc[c]*inv);
}

// ---- self-loop attr = mean of incoming edge attrs; one block per graph ----
__global__ __launch_bounds__(192) void k_loopea(const int* __restrict__ eidx, const void* ea,
                                                const int* flagp, float* lea)
{
    __shared__ float s0[A_], s1[A_];
    __shared__ int cnt[A_];
    const int f = *flagp;
    int g = blockIdx.x;
    int tid = threadIdx.x;
    if (tid < A_){ s0[tid] = 0.f; s1[tid] = 0.f; cnt[tid] = 0; }
    __syncthreads();
    if (tid < E_){
        int d = eidx[E_ + tid];
        float a0 = ldf(ea, (size_t)(g*E_+tid)*2,   f);
        float a1 = ldf(ea, (size_t)(g*E_+tid)*2+1, f);
        atomicAdd(&s0[d], a0);
        atomicAdd(&s1[d], a1);
        atomicAdd(&cnt[d], 1);
    }
    __syncthreads();
    if (tid < A_){
        int c = cnt[tid] < 1 ? 1 : cnt[tid];
        lea[(g*A_+tid)*2]   = s0[tid]/(float)c;
        lea[(g*A_+tid)*2+1] = s1[tid]/(float)c;
    }
}

// ---- fused GATv2 (v2): one block per graph; LDS-staged node features,
// register-cached weights; logits + segment softmax + aggregate ----
__global__ __launch_bounds__(256) void k_gat2(
    bfp xlr, const float* __restrict__ lea, const int* __restrict__ eidx, const void* ea,
    const bf16* __restrict__ gweb, const bf16* __restrict__ gattb,
    const void* gbias, size_t gbOff, const int* flagp, float* xf)
{
    __shared__ short X[12*2304];
    __shared__ float sAl[E2_][H_];
    __shared__ int es[E2_], ed[E2_];
    __shared__ int nl[A_][A_];
    __shared__ int ncnt[A_];
    const int f = *flagp;
    int g = blockIdx.x;
    int tid = threadIdx.x;
    int w = tid >> 6, lane = tid & 63;
    // register-cache per-lane weight strips (same for all 4 waves)
    float wg0[18], wg1[18], wga[18];
    #pragma unroll
    for (int j=0;j<18;j++){
        int hc = (j/3)*192 + (j%3)*64 + lane;
        wg0[j] = b2f(gweb[hc]);
        wg1[j] = b2f(gweb[1152+hc]);
        wga[j] = b2f(gattb[hc]);
    }
    // stage node features (27648 bf16 contiguous) via short8
    {
        const short8* src = (const short8*)(xlr + (size_t)g*A_*2304);
        short8* dst = (short8*)X;
        for (int i = tid; i < 12*2304/8; i += 256) dst[i] = src[i];
    }
    if (tid < A_) ncnt[tid] = 0;
    if (tid < E_){ es[tid] = eidx[tid]; ed[tid] = eidx[E_+tid]; }
    else if (tid < E2_){ es[tid] = tid - E_; ed[tid] = tid - E_; }
    __syncthreads();
    if (tid < E2_){
        int d = ed[tid];
        int pos = atomicAdd(&ncnt[d], 1);
        nl[d][pos] = tid;
    }
    __syncthreads();
    // phase 1: edge logits (4 waves x 36 edges)
    for (int e = w; e < E2_; e += 4){
        int s = es[e], d = ed[e];
        float f0, f1;
        if (e < E_){
            f0 = ldf(ea, (size_t)(g*E_+e)*2,   f);
            f1 = ldf(ea, (size_t)(g*E_+e)*2+1, f);
        } else {
            f0 = lea[(g*A_+s)*2]; f1 = lea[(g*A_+s)*2+1];
        }
        const short* xs = &X[s*2304];
        const short* xd = &X[d*2304 + 1152];
        #pragma unroll
        for (int h=0; h<H_; h++){
            float p = 0.f;
            #pragma unroll
            for (int c3=0; c3<3; c3++){
                int j = h*3 + c3;
                int hc = h*192 + c3*64 + lane;
                float m = s2f(xs[hc]) + s2f(xd[hc]) + f0*wg0[j] + f1*wg1[j];
                m = m > 0.f ? m : 0.2f*m;
                p += m * wga[j];
            }
            #pragma unroll
            for (int off=32; off; off>>=1) p += __shfl_xor(p, off);
            if (lane==0) sAl[e][h] = p;
        }
    }
    __syncthreads();
    // phase 2: segment softmax per (node, head); disjoint edge sets
    if (tid < A_*H_){
        int a = tid / H_, h = tid % H_;
        float m = -1e30f;
        #pragma unroll
        for (int j2=0;j2<A_;j2++) m = fmaxf(m, sAl[nl[a][j2]][h]);
        float den = 0.f;
        float ex[A_];
        #pragma unroll
        for (int j2=0;j2<A_;j2++){ ex[j2] = expf(sAl[nl[a][j2]][h]-m); den += ex[j2]; }
        float inv = 1.f/den;
        #pragma unroll
        for (int j2=0;j2<A_;j2++) sAl[nl[a][j2]][h] = ex[j2]*inv;
    }
    __syncthreads();
    // phase 3: aggregate from LDS
    int bb = g / T_, t = g % T_;
    for (int oi = tid; oi < A_*192; oi += 256){
        int a = oi / 192, c = oi % 192;
        float acc = 0.f;
        #pragma unroll
        for (int j2=0;j2<A_;j2++){
            int e = nl[a][j2];
            const short* xp = &X[es[e]*2304 + c];
            #pragma unroll
            for (int h=0;h<H_;h++) acc += sAl[e][h]*s2f(xp[h*192]);
        }
        int xrow = (bb*A_ + a)*T_ + t;
        xf[(size_t)xrow*192 + c] += acc*(1.f/6.f) + ldf(gbias, gbOff + c, f);
    }
}

__global__ __launch_bounds__(256) void k_store(const float* __restrict__ xf, void* out, const int* flagp)
{
    const int f = *flagp;
    int i = blockIdx.x*256 + threadIdx.x;
    if (i < ROWS_*192){
        if (f) ((bf16*)out)[1474560 + i] = __float2bfloat16(xf[i]);
        else   ((float*)out)[1474560 + i] = xf[i];
    }
}

extern "C" void kernel_launch(void* const* d_in, const int* in_sizes, int n_in,
                              void* d_out, int out_size, void* d_ws, size_t ws_size,
                              hipStream_t stream)
{
    const void* sf   = d_in[0];
    const int* ids  = (const int*)d_in[2];
    const int* eidx = (const int*)d_in[3];
    const void* ea   = d_in[4];
    const void* emb  = d_in[5];
    const void *laW1=d_in[6],  *lab1=d_in[7];
    const void *bn1g=d_in[8],  *bn1b=d_in[9],  *bn1m=d_in[10], *bn1v=d_in[11];
    const void *laW2=d_in[12], *lab2=d_in[13];
    const void *bn2g=d_in[14], *bn2b=d_in[15], *bn2m=d_in[16], *bn2v=d_in[17];
    const void *laW3=d_in[18], *lab3=d_in[19];
    const void *bn3g=d_in[20], *bn3b=d_in[21], *bn3m=d_in[22], *bn3v=d_in[23];
    const void *ln1g=d_in[24], *ln1b=d_in[25];
    const void *qkvw=d_in[26], *qkvb=d_in[27];
    const void *outw=d_in[28], *outb=d_in[29];
    const void *ln2g=d_in[30], *ln2b=d_in[31];
    const void *fw1 =d_in[32], *fb1 =d_in[33];
    const void *fw2 =d_in[34], *fb2 =d_in[35];
    const void *gwl =d_in[36], *gbl =d_in[37];
    const void *gwr =d_in[38], *gbr =d_in[39];
    const void *gwe =d_in[40];
    const void *gatt=d_in[41];
    const void *gbias=d_in[42];
    const void *ng  =d_in[43], *nb  =d_in[44];

    float* ws = (float*)d_ws;
    // layout (f32 units); peak ~13 M f32 = 52 MB
    float* xf  = ws;                          // [0, 1474560)
    bf16*  xn  = (bf16*)(ws + 1474560);       // 1,474,560 bf16
    bf16*  qkv = (bf16*)(ws + 2211840);       // 4,423,680 bf16
    bf16*  ao  = (bf16*)(ws + 4423680);       // 1,474,560 bf16
    bf16*  hb  = (bf16*)(ws + 2211840);       // overlays qkv+ao (FFN hidden)
    bf16*  h2  = (bf16*)(ws + 2211840);       // overlays (MLP hidden)
    bf16*  xlr = (bf16*)(ws + 2211840);       // overlays (GAT full lr: 17,694,720 bf16)
    float* lea = ws + 11059200;               // 15,360
    int*  flag = (int*)(ws + 11074560);
    bf16*  WB  = (bf16*)(ws + 11074568);      // 2,731,136 bf16
    float* BB  = ws + 12440136;               // 12,608 f32
    (void)ws_size; (void)in_sizes; (void)n_in; (void)out_size;

    k_detect<<<1, 1, 0, stream>>>(sf, flag);
    k_convert<<<(WB_TOT+BB_TOT+255)/256, 256, 0, stream>>>(
        qkvw, outw, fw1, fw2, gwl, gwr, gwe, gatt,
        laW1, lab1, bn1g, bn1b, bn1m, bn1v,
        laW2, lab2, bn2g, bn2b, bn2m, bn2v,
        laW3, lab3, bn3g, bn3b, bn3m, bn3v,
        qkvb, outb, fb1, fb2, gbl, gbr, flag, WB, BB);
    k_mlp_a<<<ROWS_/16, 256, 0, stream>>>(sf, ids, emb, flag, WB, BB, h2);
    k_mgemm<<<dim3(ROWS_/64, 3), 256, 0, stream>>>(h2, WB + WB_W3T, BB + BB_B3,
        nullptr, xf, nullptr, d_out, flag, 256, 192, 3);
    k_loopea<<<G_, 192, 0, stream>>>(eidx, ea, flag, lea);

    for (int l=0; l<3; l++){
        k_ln<<<ROWS_/4, 256, 0, stream>>>(xf, ln1g, ln1b, (size_t)l*192, flag, xn, 0);
        k_mgemm<<<dim3(ROWS_/64, 9), 256, 0, stream>>>(xn, WB + WB_QKV + (size_t)l*110592,
            BB + BB_QKV + l*576, qkv, nullptr, nullptr, nullptr, nullptr, 192, 576, 0);
        k_attn<<<N_*H_*5, 64, 0, stream>>>(qkv, ao);
        k_mgemm<<<dim3(ROWS_/64, 3), 256, 0, stream>>>(ao, WB + WB_OUT + (size_t)l*36864,
            BB + BB_OUT + l*192, nullptr, xf, xf, nullptr, nullptr, 192, 192, 2);
        k_ln<<<ROWS_/4, 256, 0, stream>>>(xf, ln2g, ln2b, (size_t)l*192, flag, xn, 0);
        k_mgemm<<<dim3(ROWS_/64, 12), 256, 0, stream>>>(xn, WB + WB_FW1 + (size_t)l*147456,
            BB + BB_FW1 + l*768, hb, nullptr, nullptr, nullptr, nullptr, 192, 768, 1);
        k_mgemm<<<dim3(ROWS_/64, 3), 256, 0, stream>>>(hb, WB + WB_FW2 + (size_t)l*147456,
            BB + BB_FW2 + l*192, nullptr, xf, xf, nullptr, nullptr, 768, 192, 2);
        k_ln<<<ROWS_/4, 256, 0, stream>>>(xf, ng, nb, (size_t)l*192, flag, xn, 1);
        k_mgemm<<<dim3(ROWS_/64, 36), 256, 0, stream>>>(xn, WB + WB_GAT + (size_t)l*442368,
            BB + BB_GAT + l*2304, xlr, nullptr, nullptr, nullptr, nullptr, 192, 2304, 0);
        k_gat2<<<G_, 256, 0, stream>>>(xlr, lea, eidx, ea,
            WB + WB_GWE + (size_t)l*2304, WB + WB_GATT + (size_t)l*1152,
            gbias, (size_t)l*192, flag, xf);
    }
    k_store<<<(ROWS_*192+255)/256, 256, 0, stream>>>(xf, d_out, flag);
}

// Round 10
// 1041.950 us; speedup vs baseline: 1.1858x; 1.1858x over previous
//
#include <hip/hip_runtime.h>
#include <hip/hip_bf16.h>
#include <math.h>

#define A_   12
#define H_   6
#define N_   96
#define T_   80
#define G_   640
#define E_   132
#define E2_  144
#define ROWS_ 7680

typedef const __hip_bfloat16* bfp;
typedef __hip_bfloat16 bf16;
typedef __attribute__((ext_vector_type(8))) short short8;
typedef __attribute__((ext_vector_type(4))) short short4v;
typedef __attribute__((ext_vector_type(4))) float f32x4;

// ---- bf16 weight arena element offsets (in bf16 units) ----
#define WB_QKV   0                /* [3][576][192]  */
#define WB_OUT   331776           /* [3][192][192]  */
#define WB_FW1   442368           /* [3][768][192]  */
#define WB_FW2   884736           /* [3][192][768]  */
#define WB_GAT   1327104          /* [3][2304][192] (gwl|gwr) */
#define WB_W1    2654208          /* [16][64] BN-folded */
#define WB_W2    2655232          /* [64][256] BN-folded */
#define WB_W3T   2671616          /* [192][256] BN-folded, transposed */
#define WB_GWE   2720768          /* [3][2304] */
#define WB_GATT  2727680          /* [3][1152] */
#define WB_TOT   2731136
// ---- f32 bias arena element offsets ----
#define BB_QKV   0                /* [3][576] */
#define BB_OUT   1728             /* [3][192] */
#define BB_FW1   2304             /* [3][768] */
#define BB_FW2   4608             /* [3][192] */
#define BB_GAT   5184             /* [3][2304] */
#define BB_B1    12096            /* [64]  folded */
#define BB_B2    12160            /* [256] folded */
#define BB_B3    12416            /* [192] folded */
#define BB_TOT   12608

__device__ __forceinline__ float b2f(bf16 x){ return __bfloat162float(x); }
__device__ __forceinline__ float ldf(const void* p, size_t i, int f){
    return f ? __bfloat162float(((const bf16*)p)[i]) : ((const float*)p)[i];
}

// dtype probe: even uint16s of f32 storage are random mantissa halves.
__global__ void k_detect(const void* sf, int* flag)
{
    const unsigned short* u = (const unsigned short*)sf;
    int sane = 0;
    for (int i = 0; i < 64; i++){
        unsigned short v = u[2*i];
        int e = (v >> 7) & 0xFF;
        if (e == 0 || (e >= 100 && e <= 140)) sane++;
    }
    *flag = (sane >= 48) ? 1 : 0;
}

// ---- convert+transpose all weights into bf16 arena; biases (BN-folded) into f32 arena ----
__global__ __launch_bounds__(256) void k_convert(
    const void* qkvw, const void* outw, const void* fw1, const void* fw2,
    const void* gwl, const void* gwr, const void* gwe, const void* gatt,
    const void* W1, const void* b1, const void* g1, const void* be1, const void* m1, const void* v1,
    const void* W2, const void* b2, const void* g2, const void* be2, const void* m2, const void* v2,
    const void* W3, const void* b3, const void* g3, const void* be3, const void* m3, const void* v3,
    const void* qkvb, const void* outb, const void* fb1, const void* fb2,
    const void* gbl, const void* gbr,
    const int* flagp, bf16* WB, float* BB)
{
    const int f = *flagp;
    size_t idx = (size_t)blockIdx.x*256 + threadIdx.x;
    if (idx < WB_TOT){
        float v;
        if (idx < WB_OUT){            size_t i=idx-WB_QKV; int l=i/110592; int r=i%110592; int n=r/192, k=r%192;
            v = ldf(qkvw, (size_t)l*110592 + (size_t)k*576 + n, f);
        } else if (idx < WB_FW1){     size_t i=idx-WB_OUT; int l=i/36864; int r=i%36864; int n=r/192, k=r%192;
            v = ldf(outw, (size_t)l*36864 + (size_t)k*192 + n, f);
        } else if (idx < WB_FW2){     size_t i=idx-WB_FW1; int l=i/147456; int r=i%147456; int n=r/192, k=r%192;
            v = ldf(fw1, (size_t)l*147456 + (size_t)k*768 + n, f);
        } else if (idx < WB_GAT){     size_t i=idx-WB_FW2; int l=i/147456; int r=i%147456; int n=r/768, k=r%768;
            v = ldf(fw2, (size_t)l*147456 + (size_t)k*192 + n, f);
        } else if (idx < WB_W1){      size_t i=idx-WB_GAT; int l=i/442368; int r=i%442368; int n=r/192, k=r%192;
            if (n < 1152) v = ldf(gwl, (size_t)l*221184 + (size_t)k*1152 + n, f);
            else          v = ldf(gwr, (size_t)l*221184 + (size_t)k*1152 + (n-1152), f);
        } else if (idx < WB_W2){      size_t i=idx-WB_W1; int o=i%64;
            float s = ldf(g1,o,f)*rsqrtf(ldf(v1,o,f)+1e-5f);
            v = ldf(W1, i, f) * s;
        } else if (idx < WB_W3T){     size_t i=idx-WB_W2; int o=i%256;
            float s = ldf(g2,o,f)*rsqrtf(ldf(v2,o,f)+1e-5f);
            v = ldf(W2, i, f) * s;
        } else if (idx < WB_GWE){     size_t i=idx-WB_W3T; int n=i/256, k=i%256;
            float s = ldf(g3,n,f)*rsqrtf(ldf(v3,n,f)+1e-5f);
            v = ldf(W3, (size_t)k*192 + n, f) * s;
        } else if (idx < WB_GATT){    size_t i=idx-WB_GWE;
            v = ldf(gwe, i, f);
        } else {                      size_t i=idx-WB_GATT;
            v = ldf(gatt, i, f);
        }
        WB[idx] = __float2bfloat16(v);
    } else if (idx < WB_TOT + BB_TOT){
        size_t j = idx - WB_TOT;
        float v;
        if (j < BB_OUT)        v = ldf(qkvb, j, f);
        else if (j < BB_FW1)   v = ldf(outb, j-BB_OUT, f);
        else if (j < BB_FW2)   v = ldf(fb1, j-BB_FW1, f);
        else if (j < BB_GAT)   v = ldf(fb2, j-BB_FW2, f);
        else if (j < BB_B1){   size_t i=j-BB_GAT; int l=i/2304; int o=i%2304;
            v = (o<1152) ? ldf(gbl, (size_t)l*1152+o, f) : ldf(gbr, (size_t)l*1152+o-1152, f);
        } else if (j < BB_B2){ int o=j-BB_B1;
            float s = ldf(g1,o,f)*rsqrtf(ldf(v1,o,f)+1e-5f);
            v = (ldf(b1,o,f)-ldf(m1,o,f))*s + ldf(be1,o,f);
        } else if (j < BB_B3){ int o=j-BB_B2;
            float s = ldf(g2,o,f)*rsqrtf(ldf(v2,o,f)+1e-5f);
            v = (ldf(b2,o,f)-ldf(m2,o,f))*s + ldf(be2,o,f);
        } else {               int o=j-BB_B3;
            float s = ldf(g3,o,f)*rsqrtf(ldf(v3,o,f)+1e-5f);
            v = (ldf(b3,o,f)-ldf(m3,o,f))*s + ldf(be3,o,f);
        }
        BB[j] = v;
    }
}

// ---- MLP stages 1+2: in16 -> 64 -> 256 (relu, BN folded), 16 rows/block ----
__global__ __launch_bounds__(256) void k_mlp_a(
    const void* sf, const int* ids, const void* emb, const int* flagp,
    const bf16* __restrict__ WB, const float* __restrict__ BB, bf16* h2g)
{
    __shared__ float in16[16][16];
    __shared__ float h1[16][64];
    const int f = *flagp;
    int tid = threadIdx.x;
    int row0 = blockIdx.x * 16;
    {
        int r = tid >> 4, i = tid & 15;
        int row = row0 + r;
        float v;
        if (i < 4) v = ldf(sf, (size_t)row*4 + i, f);
        else {
            int id = ids[row / T_]; if (id < 0) id = 0; if (id > 599) id = 599;
            v = ldf(emb, (size_t)id*12 + (i-4), f);
        }
        in16[r][i] = v;
    }
    __syncthreads();
    {
        int o = tid & 63, rg = tid >> 6;
        float acc[4];
        float bv = BB[BB_B1 + o];
        #pragma unroll
        for (int j=0;j<4;j++) acc[j] = bv;
        for (int i=0;i<16;i++){
            float w = b2f(WB[WB_W1 + i*64 + o]);
            #pragma unroll
            for (int j=0;j<4;j++) acc[j] += in16[rg*4+j][i]*w;
        }
        #pragma unroll
        for (int j=0;j<4;j++) h1[rg*4+j][o] = acc[j] > 0.f ? acc[j] : 0.f;
    }
    __syncthreads();
    {
        int o = tid;
        float acc[16];
        float bv = BB[BB_B2 + o];
        #pragma unroll
        for (int r=0;r<16;r++) acc[r] = bv;
        for (int i=0;i<64;i++){
            float w = b2f(WB[WB_W2 + i*256 + o]);
            #pragma unroll
            for (int r=0;r<16;r++) acc[r] += h1[r][i]*w;
        }
        for (int r=0;r<16;r++){
            float v = acc[r] > 0.f ? acc[r] : 0.f;
            h2g[(size_t)(row0+r)*256 + o] = __float2bfloat16(v);
        }
    }
}

// ---- MFMA GEMM: C[rows x N] = A[rows x K](bf16) @ Wt[N x K]^T + bias ----
// mode 0: bf16 store | 1: GELU bf16 | 2: outf = res + v | 3: relu -> out0(flag dtype) & xf = relu + PE
__global__ __launch_bounds__(256) void k_mgemm(
    const bf16* __restrict__ A, const bf16* __restrict__ Wt, const float* __restrict__ bias,
    bf16* outh, float* outf, const float* __restrict__ res, void* out0, const int* flagp,
    int K, int N, int mode)
{
    __shared__ short As[64*200];
    __shared__ short Bs[64*200];
    int tid = threadIdx.x;
    int w = tid >> 6, lane = tid & 63, q = lane >> 4, li = lane & 15;
    int m0 = blockIdx.x * 64, n0 = blockIdx.y * 64;
    const int f = flagp ? *flagp : 0;
    f32x4 acc[4];
    #pragma unroll
    for (int nt=0;nt<4;nt++) acc[nt] = (f32x4){0.f,0.f,0.f,0.f};
    int nkc = (K + 191) / 192;
    for (int kc = 0; kc < nkc; kc++){
        int kcw = K - kc*192; if (kcw > 192) kcw = 192;
        int vr = kcw >> 3;
        const bf16* Ab = A  + (size_t)m0*K + kc*192;
        const bf16* Bb = Wt + (size_t)n0*K + kc*192;
        for (int idx = tid; idx < 64*vr; idx += 256){
            int r = idx / vr, kv = idx - r*vr;
            *(short8*)&As[r*200 + kv*8] = *(const short8*)&Ab[(size_t)r*K + kv*8];
        }
        for (int idx = tid; idx < 64*vr; idx += 256){
            int r = idx / vr, kv = idx - r*vr;
            *(short8*)&Bs[r*200 + kv*8] = *(const short8*)&Bb[(size_t)r*K + kv*8];
        }
        __syncthreads();
        int kkn = kcw >> 5;
        for (int kk = 0; kk < kkn; kk++){
            int ko = kk*32 + q*8;
            short8 a = *(short8*)&As[(w*16+li)*200 + ko];
            #pragma unroll
            for (int nt = 0; nt < 4; nt++){
                short8 b = *(short8*)&Bs[(nt*16+li)*200 + ko];
                acc[nt] = __builtin_amdgcn_mfma_f32_16x16x32_bf16(a, b, acc[nt], 0, 0, 0);
            }
        }
        __syncthreads();
    }
    int rb = m0 + w*16 + q*4;
    #pragma unroll
    for (int nt = 0; nt < 4; nt++){
        int col = n0 + nt*16 + li;
        float bv = bias[col];
        #pragma unroll
        for (int p = 0; p < 4; p++){
            int row = rb + p;
            float v = acc[nt][p] + bv;
            size_t idx = (size_t)row*N + col;
            if (mode == 0) outh[idx] = __float2bfloat16(v);
            else if (mode == 1) outh[idx] = __float2bfloat16(0.5f*v*(1.f + erff(v*0.70710678118654752f)));
            else if (mode == 2) outf[idx] = v + res[idx];
            else {
                float r2 = v > 0.f ? v : 0.f;
                if (f) ((bf16*)out0)[idx] = __float2bfloat16(r2);
                else   ((float*)out0)[idx] = r2;
                int t = row % T_;
                int i2 = col & ~1;
                float dv = expf((float)i2 * (-9.210340371976184f/192.f));
                float ang = (float)t * dv;
                outf[idx] = r2 + ((col & 1) ? cosf(ang) : sinf(ang));
            }
        }
    }
}

// ---- LayerNorm (one wave per row), optional permute to node order ----
__global__ __launch_bounds__(256) void k_ln(const float* __restrict__ x, const void* g, const void* b,
                     size_t gOff, const int* flagp, bf16* out, int permute)
{
    const int f = *flagp;
    int tid = threadIdx.x;
    int row = blockIdx.x*4 + (tid>>6);
    int lane = tid & 63;
    const float* xr = x + (size_t)row*192;
    float v0 = xr[lane], v1 = xr[lane+64], v2 = xr[lane+128];
    float s = v0+v1+v2;
    float qq = v0*v0+v1*v1+v2*v2;
    #pragma unroll
    for (int off=32; off; off>>=1){ s += __shfl_xor(s, off); qq += __shfl_xor(qq, off); }
    float mean = s * (1.f/192.f);
    float var  = qq * (1.f/192.f) - mean*mean;
    float rs = rsqrtf(var + 1e-5f);
    int orow = row;
    if (permute){ int n = row/T_, t = row%T_; int bb = n/A_, a = n%A_; orow = (bb*T_+t)*A_ + a; }
    bf16* op = out + (size_t)orow*192;
    op[lane]     = __float2bfloat16((v0-mean)*rs*ldf(g,gOff+lane,f)     + ldf(b,gOff+lane,f));
    op[lane+64]  = __float2bfloat16((v1-mean)*rs*ldf(g,gOff+lane+64,f)  + ldf(b,gOff+lane+64,f));
    op[lane+128] = __float2bfloat16((v2-mean)*rs*ldf(g,gOff+lane+128,f) + ldf(b,gOff+lane+128,f));
}

// ---- causal attention, one wave per (seq, head, 16-query tile); online softmax ----
__global__ __launch_bounds__(64) void k_attn(bfp qkv, bf16* attn_o)
{
    __shared__ float Ks[80][32];
    __shared__ float Vs[80][32];
    int bid = blockIdx.x;
    int qt = bid % 5;
    int nh = bid / 5;
    int n = nh / H_, h = nh % H_;
    int tid = threadIdx.x;
    for (int idx = tid; idx < 640; idx += 64){
        int r = idx >> 3, c4 = (idx & 7) << 2;
        const bf16* rp = qkv + (size_t)(n*T_+r)*576 + h*32 + c4;
        short4v kv = *(const short4v*)(rp + 192);
        short4v vv = *(const short4v*)(rp + 384);
        f32x4 kf, vf;
        #pragma unroll
        for (int e=0;e<4;e++){
            kf[e] = __uint_as_float(((unsigned)(unsigned short)kv[e])<<16);
            vf[e] = __uint_as_float(((unsigned)(unsigned short)vv[e])<<16);
        }
        *(f32x4*)&Ks[r][c4] = kf;
        *(f32x4*)&Vs[r][c4] = vf;
    }
    __syncthreads();
    int qi = tid & 15, p = tid >> 4;
    int q = qt*16 + qi;
    float qv[8];
    const bf16* qp = qkv + (size_t)(n*T_+q)*576 + h*32 + p*8;
    #pragma unroll
    for (int c=0;c<8;c++) qv[c] = b2f(qp[c]);
    float m = -1e30f, l = 0.f;
    float acc[8];
    #pragma unroll
    for (int c=0;c<8;c++) acc[c]=0.f;
    int jmax = qt*16 + 15;
    for (int j = 0; j <= jmax; j++){
        float s = 0.f;
        #pragma unroll
        for (int c=0;c<8;c++) s += qv[c]*Ks[j][p*8+c];
        s += __shfl_xor(s, 16);
        s += __shfl_xor(s, 32);
        s *= 0.17677669529663687f;
        if (j > q) s = -1e30f;
        float mn = fmaxf(m, s);
        float corr = expf(m - mn);
        float e = expf(s - mn);
        l = l*corr + e;
        #pragma unroll
        for (int c=0;c<8;c++) acc[c] = acc[c]*corr + e*Vs[j][p*8+c];
        m = mn;
    }
    float inv = 1.f/l;
    bf16* op = attn_o + (size_t)(n*T_+q)*192 + h*32 + p*8;
    #pragma unroll
    for (int c=0;c<8;c++) op[c] = __float2bfloat16(acc[c]*inv);
}

// ---- self-loop attr = mean of incoming edge attrs; one block per graph ----
__global__ __launch_bounds__(192) void k_loopea(const int* __restrict__ eidx, const void* ea,
                                                const int* flagp, float* lea)
{
    __shared__ float s0[A_], s1[A_];
    __shared__ int cnt[A_];
    const int f = *flagp;
    int g = blockIdx.x;
    int tid = threadIdx.x;
    if (tid < A_){ s0[tid] = 0.f; s1[tid] = 0.f; cnt[tid] = 0; }
    __syncthreads();
    if (tid < E_){
        int d = eidx[E_ + tid];
        float a0 = ldf(ea, (size_t)(g*E_+tid)*2,   f);
        float a1 = ldf(ea, (size_t)(g*E_+tid)*2+1, f);
        atomicAdd(&s0[d], a0);
        atomicAdd(&s1[d], a1);
        atomicAdd(&cnt[d], 1);
    }
    __syncthreads();
    if (tid < A_){
        int c = cnt[tid] < 1 ? 1 : cnt[tid];
        lea[(g*A_+tid)*2]   = s0[tid]/(float)c;
        lea[(g*A_+tid)*2+1] = s1[tid]/(float)c;
    }
}

// ---- GAT edge logits v2: one wave per (graph, dst); complete-graph structure.
// alpha stored dense: [(g*A+d)*A + s][H]. Edge (s,d), s!=d has el = s*11 + (d<s ? d : d-1).
__global__ __launch_bounds__(256) void k_alpha(bfp xlr,
                        const float* __restrict__ lea, const void* ea,
                        const bf16* __restrict__ gweb, const bf16* __restrict__ gattb,
                        const int* flagp, float* alpha)
{
    const int f = *flagp;
    int wid = blockIdx.x*4 + (threadIdx.x>>6);
    int lane = threadIdx.x & 63;
    int g = wid / A_, d = wid % A_;
    // register caches: xr[d] strips + weight strips
    float xrd[18], wg0[18], wg1[18], wga[18];
    const bf16* xrp = xlr + (size_t)(g*A_+d)*2304 + 1152;
    #pragma unroll
    for (int j=0;j<18;j++){
        int hc = (j/3)*192 + (j%3)*64 + lane;
        xrd[j] = b2f(xrp[hc]);
        wg0[j] = b2f(gweb[hc]);
        wg1[j] = b2f(gweb[1152+hc]);
        wga[j] = b2f(gattb[hc]);
    }
    float* ap = alpha + (size_t)wid*72;
    for (int s = 0; s < A_; s++){
        float f0, f1;
        if (s == d){
            f0 = lea[(g*A_+s)*2]; f1 = lea[(g*A_+s)*2+1];
        } else {
            int el = s*11 + (d < s ? d : d-1);
            f0 = ldf(ea, (size_t)(g*E_+el)*2,   f);
            f1 = ldf(ea, (size_t)(g*E_+el)*2+1, f);
        }
        const bf16* xls = xlr + (size_t)(g*A_+s)*2304;
        #pragma unroll
        for (int h=0; h<H_; h++){
            float p = 0.f;
            #pragma unroll
            for (int c3=0; c3<3; c3++){
                int j = h*3 + c3;
                int hc = h*192 + c3*64 + lane;
                float m = b2f(xls[hc]) + xrd[j] + f0*wg0[j] + f1*wg1[j];
                m = m > 0.f ? m : 0.2f*m;
                p += m * wga[j];
            }
            #pragma unroll
            for (int off=32; off; off>>=1) p += __shfl_xor(p, off);
            if (lane==0) ap[s*H_ + h] = p;
        }
    }
}

// ---- GAT segment softmax + aggregate, one block per dst node; dense alpha ----
__global__ __launch_bounds__(192) void k_segagg(bfp xlr, const float* __restrict__ alpha,
                         const void* gbias, size_t gbOff, const int* flagp, float* xf)
{
    __shared__ float al[12][6];
    __shared__ float w[12][6];
    const int f = *flagp;
    int node = blockIdx.x;
    int gl = node / A_, a = node % A_;
    int tid = threadIdx.x;
    if (tid < 72) ((float*)al)[tid] = alpha[(size_t)node*72 + tid];
    __syncthreads();
    if (tid < 6){
        float m = -1e30f;
        #pragma unroll
        for (int s=0;s<12;s++) m = fmaxf(m, al[s][tid]);
        float den = 0.f;
        #pragma unroll
        for (int s=0;s<12;s++){ float ex = expf(al[s][tid]-m); w[s][tid] = ex; den += ex; }
        float inv = 1.f/den;
        #pragma unroll
        for (int s=0;s<12;s++) w[s][tid] *= inv;
    }
    __syncthreads();
    int c = tid;
    float acc = 0.f;
    for (int s=0;s<12;s++){
        const bf16* xp = xlr + (size_t)(gl*A_ + s)*2304 + c;
        #pragma unroll
        for (int h=0;h<6;h++) acc += w[s][h]*b2f(xp[h*192]);
    }
    int b = gl / T_, t = gl % T_;
    int xrow = (b*A_ + a)*T_ + t;
    xf[(size_t)xrow*192 + c] += acc*(1.f/6.f) + ldf(gbias, gbOff + c, f);
}

__global__ __launch_bounds__(256) void k_store(const float* __restrict__ xf, void* out, const int* flagp)
{
    const int f = *flagp;
    int i = blockIdx.x*256 + threadIdx.x;
    if (i < ROWS_*192){
        if (f) ((bf16*)out)[1474560 + i] = __float2bfloat16(xf[i]);
        else   ((float*)out)[1474560 + i] = xf[i];
    }
}

extern "C" void kernel_launch(void* const* d_in, const int* in_sizes, int n_in,
                              void* d_out, int out_size, void* d_ws, size_t ws_size,
                              hipStream_t stream)
{
    const void* sf   = d_in[0];
    const int* ids  = (const int*)d_in[2];
    const int* eidx = (const int*)d_in[3];
    const void* ea   = d_in[4];
    const void* emb  = d_in[5];
    const void *laW1=d_in[6],  *lab1=d_in[7];
    const void *bn1g=d_in[8],  *bn1b=d_in[9],  *bn1m=d_in[10], *bn1v=d_in[11];
    const void *laW2=d_in[12], *lab2=d_in[13];
    const void *bn2g=d_in[14], *bn2b=d_in[15], *bn2m=d_in[16], *bn2v=d_in[17];
    const void *laW3=d_in[18], *lab3=d_in[19];
    const void *bn3g=d_in[20], *bn3b=d_in[21], *bn3m=d_in[22], *bn3v=d_in[23];
    const void *ln1g=d_in[24], *ln1b=d_in[25];
    const void *qkvw=d_in[26], *qkvb=d_in[27];
    const void *outw=d_in[28], *outb=d_in[29];
    const void *ln2g=d_in[30], *ln2b=d_in[31];
    const void *fw1 =d_in[32], *fb1 =d_in[33];
    const void *fw2 =d_in[34], *fb2 =d_in[35];
    const void *gwl =d_in[36], *gbl =d_in[37];
    const void *gwr =d_in[38], *gbr =d_in[39];
    const void *gwe =d_in[40];
    const void *gatt=d_in[41];
    const void *gbias=d_in[42];
    const void *ng  =d_in[43], *nb  =d_in[44];

    float* ws = (float*)d_ws;
    // layout (f32 units); peak ~13 M f32 = 52 MB
    float* xf  = ws;                          // [0, 1474560)
    bf16*  xn  = (bf16*)(ws + 1474560);       // 1,474,560 bf16
    bf16*  qkv = (bf16*)(ws + 2211840);       // 4,423,680 bf16
    bf16*  ao  = (bf16*)(ws + 4423680);       // 1,474,560 bf16
    bf16*  hb  = (bf16*)(ws + 2211840);       // overlays qkv+ao (FFN hidden)
    bf16*  h2  = (bf16*)(ws + 2211840);       // overlays (MLP hidden)
    bf16*  xlr = (bf16*)(ws + 2211840);       // overlays (GAT full lr: 17,694,720 bf16)
    float* lea = ws + 11059200;               // 15,360
    int*  flag = (int*)(ws + 11074560);
    bf16*  WB  = (bf16*)(ws + 11074568);      // 2,731,136 bf16
    float* BB  = ws + 12440136;               // 12,608 f32
    float* alp = ws + 12452744;               // 552,960 f32 (dense [node][src][head])
    (void)ws_size; (void)in_sizes; (void)n_in; (void)out_size;

    k_detect<<<1, 1, 0, stream>>>(sf, flag);
    k_convert<<<(WB_TOT+BB_TOT+255)/256, 256, 0, stream>>>(
        qkvw, outw, fw1, fw2, gwl, gwr, gwe, gatt,
        laW1, lab1, bn1g, bn1b, bn1m, bn1v,
        laW2, lab2, bn2g, bn2b, bn2m, bn2v,
        laW3, lab3, bn3g, bn3b, bn3m, bn3v,
        qkvb, outb, fb1, fb2, gbl, gbr, flag, WB, BB);
    k_mlp_a<<<ROWS_/16, 256, 0, stream>>>(sf, ids, emb, flag, WB, BB, h2);
    k_mgemm<<<dim3(ROWS_/64, 3), 256, 0, stream>>>(h2, WB + WB_W3T, BB + BB_B3,
        nullptr, xf, nullptr, d_out, flag, 256, 192, 3);
    k_loopea<<<G_, 192, 0, stream>>>(eidx, ea, flag, lea);

    for (int l=0; l<3; l++){
        k_ln<<<ROWS_/4, 256, 0, stream>>>(xf, ln1g, ln1b, (size_t)l*192, flag, xn, 0);
        k_mgemm<<<dim3(ROWS_/64, 9), 256, 0, stream>>>(xn, WB + WB_QKV + (size_t)l*110592,
            BB + BB_QKV + l*576, qkv, nullptr, nullptr, nullptr, nullptr, 192, 576, 0);
        k_attn<<<N_*H_*5, 64, 0, stream>>>(qkv, ao);
        k_mgemm<<<dim3(ROWS_/64, 3), 256, 0, stream>>>(ao, WB + WB_OUT + (size_t)l*36864,
            BB + BB_OUT + l*192, nullptr, xf, xf, nullptr, nullptr, 192, 192, 2);
        k_ln<<<ROWS_/4, 256, 0, stream>>>(xf, ln2g, ln2b, (size_t)l*192, flag, xn, 0);
        k_mgemm<<<dim3(ROWS_/64, 12), 256, 0, stream>>>(xn, WB + WB_FW1 + (size_t)l*147456,
            BB + BB_FW1 + l*768, hb, nullptr, nullptr, nullptr, nullptr, 192, 768, 1);
        k_mgemm<<<dim3(ROWS_/64, 3), 256, 0, stream>>>(hb, WB + WB_FW2 + (size_t)l*147456,
            BB + BB_FW2 + l*192, nullptr, xf, xf, nullptr, nullptr, 768, 192, 2);
        k_ln<<<ROWS_/4, 256, 0, stream>>>(xf, ng, nb, (size_t)l*192, flag, xn, 1);
        k_mgemm<<<dim3(ROWS_/64, 36), 256, 0, stream>>>(xn, WB + WB_GAT + (size_t)l*442368,
            BB + BB_GAT + l*2304, xlr, nullptr, nullptr, nullptr, nullptr, 192, 2304, 0);
        k_alpha<<<G_*A_/4, 256, 0, stream>>>(xlr, lea, ea,
            WB + WB_GWE + (size_t)l*2304, WB + WB_GATT + (size_t)l*1152, flag, alp);
        k_segagg<<<G_*A_, 192, 0, stream>>>(xlr, alp, gbias, (size_t)l*192, flag, xf);
    }
    k_store<<<(ROWS_*192+255)/256, 256, 0, stream>>>(xf, d_out, flag);
}

// Round 11
// 920.326 us; speedup vs baseline: 1.3425x; 1.1322x over previous
//
#include <hip/hip_runtime.h>
#include <hip/hip_bf16.h>
#include <math.h>

#define A_   12
#define H_   6
#define N_   96
#define T_   80
#define G_   640
#define E_   132
#define E2_  144
#define ROWS_ 7680

typedef const __hip_bfloat16* bfp;
typedef __hip_bfloat16 bf16;
typedef __attribute__((ext_vector_type(8))) short short8;
typedef __attribute__((ext_vector_type(4))) short short4v;
typedef __attribute__((ext_vector_type(4))) float f32x4;

// ---- bf16 weight arena element offsets (in bf16 units) ----
#define WB_QKV   0                /* [3][576][192]  */
#define WB_OUT   331776           /* [3][192][192]  */
#define WB_FW1   442368           /* [3][768][192]  */
#define WB_FW2   884736           /* [3][192][768]  */
#define WB_GAT   1327104          /* [3][2304][192] (gwl|gwr) */
#define WB_W1    2654208          /* [16][64] BN-folded */
#define WB_W2    2655232          /* [64][256] BN-folded */
#define WB_W3T   2671616          /* [192][256] BN-folded, transposed */
#define WB_GWE   2720768          /* [3][2304] */
#define WB_GATT  2727680          /* [3][1152] */
#define WB_TOT   2731136
// ---- f32 bias arena element offsets ----
#define BB_QKV   0                /* [3][576] */
#define BB_OUT   1728             /* [3][192] */
#define BB_FW1   2304             /* [3][768] */
#define BB_FW2   4608             /* [3][192] */
#define BB_GAT   5184             /* [3][2304] */
#define BB_B1    12096            /* [64]  folded */
#define BB_B2    12160            /* [256] folded */
#define BB_B3    12416            /* [192] folded */
#define BB_TOT   12608

__device__ __forceinline__ float b2f(bf16 x){ return __bfloat162float(x); }
__device__ __forceinline__ float ldf(const void* p, size_t i, int f){
    return f ? __bfloat162float(((const bf16*)p)[i]) : ((const float*)p)[i];
}

// dtype probe: even uint16s of f32 storage are random mantissa halves.
__global__ void k_detect(const void* sf, int* flag)
{
    const unsigned short* u = (const unsigned short*)sf;
    int sane = 0;
    for (int i = 0; i < 64; i++){
        unsigned short v = u[2*i];
        int e = (v >> 7) & 0xFF;
        if (e == 0 || (e >= 100 && e <= 140)) sane++;
    }
    *flag = (sane >= 48) ? 1 : 0;
}

// ---- convert+transpose all weights into bf16 arena; biases (BN-folded) into f32 arena ----
__global__ __launch_bounds__(256) void k_convert(
    const void* qkvw, const void* outw, const void* fw1, const void* fw2,
    const void* gwl, const void* gwr, const void* gwe, const void* gatt,
    const void* W1, const void* b1, const void* g1, const void* be1, const void* m1, const void* v1,
    const void* W2, const void* b2, const void* g2, const void* be2, const void* m2, const void* v2,
    const void* W3, const void* b3, const void* g3, const void* be3, const void* m3, const void* v3,
    const void* qkvb, const void* outb, const void* fb1, const void* fb2,
    const void* gbl, const void* gbr,
    const int* flagp, bf16* WB, float* BB)
{
    const int f = *flagp;
    size_t idx = (size_t)blockIdx.x*256 + threadIdx.x;
    if (idx < WB_TOT){
        float v;
        if (idx < WB_OUT){            size_t i=idx-WB_QKV; int l=i/110592; int r=i%110592; int n=r/192, k=r%192;
            v = ldf(qkvw, (size_t)l*110592 + (size_t)k*576 + n, f);
        } else if (idx < WB_FW1){     size_t i=idx-WB_OUT; int l=i/36864; int r=i%36864; int n=r/192, k=r%192;
            v = ldf(outw, (size_t)l*36864 + (size_t)k*192 + n, f);
        } else if (idx < WB_FW2){     size_t i=idx-WB_FW1; int l=i/147456; int r=i%147456; int n=r/192, k=r%192;
            v = ldf(fw1, (size_t)l*147456 + (size_t)k*768 + n, f);
        } else if (idx < WB_GAT){     size_t i=idx-WB_FW2; int l=i/147456; int r=i%147456; int n=r/768, k=r%768;
            v = ldf(fw2, (size_t)l*147456 + (size_t)k*192 + n, f);
        } else if (idx < WB_W1){      size_t i=idx-WB_GAT; int l=i/442368; int r=i%442368; int n=r/192, k=r%192;
            if (n < 1152) v = ldf(gwl, (size_t)l*221184 + (size_t)k*1152 + n, f);
            else          v = ldf(gwr, (size_t)l*221184 + (size_t)k*1152 + (n-1152), f);
        } else if (idx < WB_W2){      size_t i=idx-WB_W1; int o=i%64;
            float s = ldf(g1,o,f)*rsqrtf(ldf(v1,o,f)+1e-5f);
            v = ldf(W1, i, f) * s;
        } else if (idx < WB_W3T){     size_t i=idx-WB_W2; int o=i%256;
            float s = ldf(g2,o,f)*rsqrtf(ldf(v2,o,f)+1e-5f);
            v = ldf(W2, i, f) * s;
        } else if (idx < WB_GWE){     size_t i=idx-WB_W3T; int n=i/256, k=i%256;
            float s = ldf(g3,n,f)*rsqrtf(ldf(v3,n,f)+1e-5f);
            v = ldf(W3, (size_t)k*192 + n, f) * s;
        } else if (idx < WB_GATT){    size_t i=idx-WB_GWE;
            v = ldf(gwe, i, f);
        } else {                      size_t i=idx-WB_GATT;
            v = ldf(gatt, i, f);
        }
        WB[idx] = __float2bfloat16(v);
    } else if (idx < WB_TOT + BB_TOT){
        size_t j = idx - WB_TOT;
        float v;
        if (j < BB_OUT)        v = ldf(qkvb, j, f);
        else if (j < BB_FW1)   v = ldf(outb, j-BB_OUT, f);
        else if (j < BB_FW2)   v = ldf(fb1, j-BB_FW1, f);
        else if (j < BB_GAT)   v = ldf(fb2, j-BB_FW2, f);
        else if (j < BB_B1){   size_t i=j-BB_GAT; int l=i/2304; int o=i%2304;
            v = (o<1152) ? ldf(gbl, (size_t)l*1152+o, f) : ldf(gbr, (size_t)l*1152+o-1152, f);
        } else if (j < BB_B2){ int o=j-BB_B1;
            float s = ldf(g1,o,f)*rsqrtf(ldf(v1,o,f)+1e-5f);
            v = (ldf(b1,o,f)-ldf(m1,o,f))*s + ldf(be1,o,f);
        } else if (j < BB_B3){ int o=j-BB_B2;
            float s = ldf(g2,o,f)*rsqrtf(ldf(v2,o,f)+1e-5f);
            v = (ldf(b2,o,f)-ldf(m2,o,f))*s + ldf(be2,o,f);
        } else {               int o=j-BB_B3;
            float s = ldf(g3,o,f)*rsqrtf(ldf(v3,o,f)+1e-5f);
            v = (ldf(b3,o,f)-ldf(m3,o,f))*s + ldf(be3,o,f);
        }
        BB[j] = v;
    }
}

// ---- MLP stages 1+2: in16 -> 64 -> 256 (relu, BN folded), 16 rows/block ----
__global__ __launch_bounds__(256) void k_mlp_a(
    const void* sf, const int* ids, const void* emb, const int* flagp,
    const bf16* __restrict__ WB, const float* __restrict__ BB, bf16* h2g)
{
    __shared__ float in16[16][16];
    __shared__ float h1[16][64];
    const int f = *flagp;
    int tid = threadIdx.x;
    int row0 = blockIdx.x * 16;
    {
        int r = tid >> 4, i = tid & 15;
        int row = row0 + r;
        float v;
        if (i < 4) v = ldf(sf, (size_t)row*4 + i, f);
        else {
            int id = ids[row / T_]; if (id < 0) id = 0; if (id > 599) id = 599;
            v = ldf(emb, (size_t)id*12 + (i-4), f);
        }
        in16[r][i] = v;
    }
    __syncthreads();
    {
        int o = tid & 63, rg = tid >> 6;
        float acc[4];
        float bv = BB[BB_B1 + o];
        #pragma unroll
        for (int j=0;j<4;j++) acc[j] = bv;
        for (int i=0;i<16;i++){
            float w = b2f(WB[WB_W1 + i*64 + o]);
            #pragma unroll
            for (int j=0;j<4;j++) acc[j] += in16[rg*4+j][i]*w;
        }
        #pragma unroll
        for (int j=0;j<4;j++) h1[rg*4+j][o] = acc[j] > 0.f ? acc[j] : 0.f;
    }
    __syncthreads();
    {
        int o = tid;
        float acc[16];
        float bv = BB[BB_B2 + o];
        #pragma unroll
        for (int r=0;r<16;r++) acc[r] = bv;
        for (int i=0;i<64;i++){
            float w = b2f(WB[WB_W2 + i*256 + o]);
            #pragma unroll
            for (int r=0;r<16;r++) acc[r] += h1[r][i]*w;
        }
        for (int r=0;r<16;r++){
            float v = acc[r] > 0.f ? acc[r] : 0.f;
            h2g[(size_t)(row0+r)*256 + o] = __float2bfloat16(v);
        }
    }
}

// ---- MFMA GEMM (64x64 tile): C = A @ Wt^T + bias ----
// mode 0: bf16 store | 1: GELU bf16 | 2: outf = res + v | 3: relu -> out0(flag dtype) & xf = relu + PE
__global__ __launch_bounds__(256) void k_mgemm(
    const bf16* __restrict__ A, const bf16* __restrict__ Wt, const float* __restrict__ bias,
    bf16* outh, float* outf, const float* __restrict__ res, void* out0, const int* flagp,
    int K, int N, int mode)
{
    __shared__ short As[64*200];
    __shared__ short Bs[64*200];
    int tid = threadIdx.x;
    int w = tid >> 6, lane = tid & 63, q = lane >> 4, li = lane & 15;
    int m0 = blockIdx.x * 64, n0 = blockIdx.y * 64;
    const int f = flagp ? *flagp : 0;
    f32x4 acc[4];
    #pragma unroll
    for (int nt=0;nt<4;nt++) acc[nt] = (f32x4){0.f,0.f,0.f,0.f};
    int nkc = (K + 191) / 192;
    for (int kc = 0; kc < nkc; kc++){
        int kcw = K - kc*192; if (kcw > 192) kcw = 192;
        int vr = kcw >> 3;
        const bf16* Ab = A  + (size_t)m0*K + kc*192;
        const bf16* Bb = Wt + (size_t)n0*K + kc*192;
        for (int idx = tid; idx < 64*vr; idx += 256){
            int r = idx / vr, kv = idx - r*vr;
            *(short8*)&As[r*200 + kv*8] = *(const short8*)&Ab[(size_t)r*K + kv*8];
        }
        for (int idx = tid; idx < 64*vr; idx += 256){
            int r = idx / vr, kv = idx - r*vr;
            *(short8*)&Bs[r*200 + kv*8] = *(const short8*)&Bb[(size_t)r*K + kv*8];
        }
        __syncthreads();
        int kkn = kcw >> 5;
        for (int kk = 0; kk < kkn; kk++){
            int ko = kk*32 + q*8;
            short8 a = *(short8*)&As[(w*16+li)*200 + ko];
            #pragma unroll
            for (int nt = 0; nt < 4; nt++){
                short8 b = *(short8*)&Bs[(nt*16+li)*200 + ko];
                acc[nt] = __builtin_amdgcn_mfma_f32_16x16x32_bf16(a, b, acc[nt], 0, 0, 0);
            }
        }
        __syncthreads();
    }
    int rb = m0 + w*16 + q*4;
    #pragma unroll
    for (int nt = 0; nt < 4; nt++){
        int col = n0 + nt*16 + li;
        float bv = bias[col];
        #pragma unroll
        for (int p = 0; p < 4; p++){
            int row = rb + p;
            float v = acc[nt][p] + bv;
            size_t idx = (size_t)row*N + col;
            if (mode == 0) outh[idx] = __float2bfloat16(v);
            else if (mode == 1) outh[idx] = __float2bfloat16(0.5f*v*(1.f + erff(v*0.70710678118654752f)));
            else if (mode == 2) outf[idx] = v + res[idx];
            else {
                float r2 = v > 0.f ? v : 0.f;
                if (f) ((bf16*)out0)[idx] = __float2bfloat16(r2);
                else   ((float*)out0)[idx] = r2;
                int t = row % T_;
                int i2 = col & ~1;
                float dv = expf((float)i2 * (-9.210340371976184f/192.f));
                float ang = (float)t * dv;
                outf[idx] = r2 + ((col & 1) ? cosf(ang) : sinf(ang));
            }
        }
    }
}

// ---- MFMA GEMM (128x64 tile, K%96==0): for wide-N GEMMs; mode 0/1 only ----
__global__ __launch_bounds__(256) void k_mgemm128(
    const bf16* __restrict__ A, const bf16* __restrict__ Wt, const float* __restrict__ bias,
    bf16* outh, int K, int N, int mode)
{
    __shared__ short As[128*104];
    __shared__ short Bs[64*104];
    int tid = threadIdx.x;
    int w = tid >> 6, lane = tid & 63, q = lane >> 4, li = lane & 15;
    int m0 = blockIdx.x * 128, n0 = blockIdx.y * 64;
    f32x4 acc[2][4];
    #pragma unroll
    for (int mt=0;mt<2;mt++)
        #pragma unroll
        for (int nt=0;nt<4;nt++) acc[mt][nt] = (f32x4){0.f,0.f,0.f,0.f};
    int nkc = K / 96;
    for (int kc = 0; kc < nkc; kc++){
        const bf16* Ab = A  + (size_t)m0*K + kc*96;
        const bf16* Bb = Wt + (size_t)n0*K + kc*96;
        for (int idx = tid; idx < 128*12; idx += 256){
            int r = idx / 12, kv = idx - r*12;
            *(short8*)&As[r*104 + kv*8] = *(const short8*)&Ab[(size_t)r*K + kv*8];
        }
        for (int idx = tid; idx < 64*12; idx += 256){
            int r = idx / 12, kv = idx - r*12;
            *(short8*)&Bs[r*104 + kv*8] = *(const short8*)&Bb[(size_t)r*K + kv*8];
        }
        __syncthreads();
        #pragma unroll
        for (int kk = 0; kk < 3; kk++){
            int ko = kk*32 + q*8;
            short8 b0 = *(short8*)&Bs[(0*16+li)*104 + ko];
            short8 b1 = *(short8*)&Bs[(1*16+li)*104 + ko];
            short8 b2 = *(short8*)&Bs[(2*16+li)*104 + ko];
            short8 b3 = *(short8*)&Bs[(3*16+li)*104 + ko];
            #pragma unroll
            for (int mt = 0; mt < 2; mt++){
                short8 a = *(short8*)&As[(w*32 + mt*16 + li)*104 + ko];
                acc[mt][0] = __builtin_amdgcn_mfma_f32_16x16x32_bf16(a, b0, acc[mt][0], 0, 0, 0);
                acc[mt][1] = __builtin_amdgcn_mfma_f32_16x16x32_bf16(a, b1, acc[mt][1], 0, 0, 0);
                acc[mt][2] = __builtin_amdgcn_mfma_f32_16x16x32_bf16(a, b2, acc[mt][2], 0, 0, 0);
                acc[mt][3] = __builtin_amdgcn_mfma_f32_16x16x32_bf16(a, b3, acc[mt][3], 0, 0, 0);
            }
        }
        __syncthreads();
    }
    #pragma unroll
    for (int mt = 0; mt < 2; mt++){
        int rb = m0 + w*32 + mt*16 + q*4;
        #pragma unroll
        for (int nt = 0; nt < 4; nt++){
            int col = n0 + nt*16 + li;
            float bv = bias[col];
            #pragma unroll
            for (int p = 0; p < 4; p++){
                float v = acc[mt][nt][p] + bv;
                size_t idx = (size_t)(rb+p)*N + col;
                if (mode == 0) outh[idx] = __float2bfloat16(v);
                else outh[idx] = __float2bfloat16(0.5f*v*(1.f + erff(v*0.70710678118654752f)));
            }
        }
    }
}

// ---- LayerNorm (one wave per row), optional permute to node order ----
__global__ __launch_bounds__(256) void k_ln(const float* __restrict__ x, const void* g, const void* b,
                     size_t gOff, const int* flagp, bf16* out, int permute)
{
    const int f = *flagp;
    int tid = threadIdx.x;
    int row = blockIdx.x*4 + (tid>>6);
    int lane = tid & 63;
    const float* xr = x + (size_t)row*192;
    float v0 = xr[lane], v1 = xr[lane+64], v2 = xr[lane+128];
    float s = v0+v1+v2;
    float qq = v0*v0+v1*v1+v2*v2;
    #pragma unroll
    for (int off=32; off; off>>=1){ s += __shfl_xor(s, off); qq += __shfl_xor(qq, off); }
    float mean = s * (1.f/192.f);
    float var  = qq * (1.f/192.f) - mean*mean;
    float rs = rsqrtf(var + 1e-5f);
    int orow = row;
    if (permute){ int n = row/T_, t = row%T_; int bb = n/A_, a = n%A_; orow = (bb*T_+t)*A_ + a; }
    bf16* op = out + (size_t)orow*192;
    op[lane]     = __float2bfloat16((v0-mean)*rs*ldf(g,gOff+lane,f)     + ldf(b,gOff+lane,f));
    op[lane+64]  = __float2bfloat16((v1-mean)*rs*ldf(g,gOff+lane+64,f)  + ldf(b,gOff+lane+64,f));
    op[lane+128] = __float2bfloat16((v2-mean)*rs*ldf(g,gOff+lane+128,f) + ldf(b,gOff+lane+128,f));
}

// ---- causal attention, one wave per (seq, head, 16-query tile); online softmax ----
__global__ __launch_bounds__(64) void k_attn(bfp qkv, bf16* attn_o)
{
    __shared__ float Ks[80][32];
    __shared__ float Vs[80][32];
    int bid = blockIdx.x;
    int qt = bid % 5;
    int nh = bid / 5;
    int n = nh / H_, h = nh % H_;
    int tid = threadIdx.x;
    for (int idx = tid; idx < 640; idx += 64){
        int r = idx >> 3, c4 = (idx & 7) << 2;
        const bf16* rp = qkv + (size_t)(n*T_+r)*576 + h*32 + c4;
        short4v kv = *(const short4v*)(rp + 192);
        short4v vv = *(const short4v*)(rp + 384);
        f32x4 kf, vf;
        #pragma unroll
        for (int e=0;e<4;e++){
            kf[e] = __uint_as_float(((unsigned)(unsigned short)kv[e])<<16);
            vf[e] = __uint_as_float(((unsigned)(unsigned short)vv[e])<<16);
        }
        *(f32x4*)&Ks[r][c4] = kf;
        *(f32x4*)&Vs[r][c4] = vf;
    }
    __syncthreads();
    int qi = tid & 15, p = tid >> 4;
    int q = qt*16 + qi;
    float qv[8];
    const bf16* qp = qkv + (size_t)(n*T_+q)*576 + h*32 + p*8;
    #pragma unroll
    for (int c=0;c<8;c++) qv[c] = b2f(qp[c]);
    float m = -1e30f, l = 0.f;
    float acc[8];
    #pragma unroll
    for (int c=0;c<8;c++) acc[c]=0.f;
    int jmax = qt*16 + 15;
    for (int j = 0; j <= jmax; j++){
        float s = 0.f;
        #pragma unroll
        for (int c=0;c<8;c++) s += qv[c]*Ks[j][p*8+c];
        s += __shfl_xor(s, 16);
        s += __shfl_xor(s, 32);
        s *= 0.17677669529663687f;
        if (j > q) s = -1e30f;
        float mn = fmaxf(m, s);
        float corr = expf(m - mn);
        float e = expf(s - mn);
        l = l*corr + e;
        #pragma unroll
        for (int c=0;c<8;c++) acc[c] = acc[c]*corr + e*Vs[j][p*8+c];
        m = mn;
    }
    float inv = 1.f/l;
    bf16* op = attn_o + (size_t)(n*T_+q)*192 + h*32 + p*8;
    #pragma unroll
    for (int c=0;c<8;c++) op[c] = __float2bfloat16(acc[c]*inv);
}

// ---- self-loop attr = mean of incoming edge attrs; one block per graph ----
__global__ __launch_bounds__(192) void k_loopea(const int* __restrict__ eidx, const void* ea,
                                                const int* flagp, float* lea)
{
    __shared__ float s0[A_], s1[A_];
    __shared__ int cnt[A_];
    const int f = *flagp;
    int g = blockIdx.x;
    int tid = threadIdx.x;
    if (tid < A_){ s0[tid] = 0.f; s1[tid] = 0.f; cnt[tid] = 0; }
    __syncthreads();
    if (tid < E_){
        int d = eidx[E_ + tid];
        float a0 = ldf(ea, (size_t)(g*E_+tid)*2,   f);
        float a1 = ldf(ea, (size_t)(g*E_+tid)*2+1, f);
        atomicAdd(&s0[d], a0);
        atomicAdd(&s1[d], a1);
        atomicAdd(&cnt[d], 1);
    }
    __syncthreads();
    if (tid < A_){
        int c = cnt[tid] < 1 ? 1 : cnt[tid];
        lea[(g*A_+tid)*2]   = s0[tid]/(float)c;
        lea[(g*A_+tid)*2+1] = s1[tid]/(float)c;
    }
}

// ---- GAT edge logits: one wave per dense (g,d,s) pair; writes dense alpha ----
// alpha layout: [(g*12+d)*12 + s][H]. Edge (s!=d) attr index = s*11 + (d<s ? d : d-1).
__global__ __launch_bounds__(256) void k_alpha(bfp xlr,
                        const float* __restrict__ lea, const void* ea,
                        const bf16* __restrict__ gweb, const bf16* __restrict__ gattb,
                        const int* flagp, float* alpha)
{
    const int f = *flagp;
    int wid = blockIdx.x*4 + (threadIdx.x>>6);
    int lane = threadIdx.x & 63;
    int g = wid / 144, ds = wid % 144;
    int d = ds / 12, s = ds % 12;
    float f0, f1;
    if (s == d){
        f0 = lea[(g*A_+s)*2]; f1 = lea[(g*A_+s)*2+1];
    } else {
        int el = s*11 + (d < s ? d : d-1);
        f0 = ldf(ea, (size_t)(g*E_+el)*2,   f);
        f1 = ldf(ea, (size_t)(g*E_+el)*2+1, f);
    }
    const bf16* xls = xlr + (size_t)(g*A_+s)*2304;
    const bf16* xrd = xlr + (size_t)(g*A_+d)*2304 + 1152;
    for (int h=0; h<H_; h++){
        float p = 0.f;
        #pragma unroll
        for (int c3=0;c3<3;c3++){
            int hc = h*192 + c3*64 + lane;
            float m = b2f(xls[hc]) + b2f(xrd[hc]) + f0*b2f(gweb[hc]) + f1*b2f(gweb[1152+hc]);
            m = m > 0.f ? m : 0.2f*m;
            p += m * b2f(gattb[hc]);
        }
        #pragma unroll
        for (int off=32; off; off>>=1) p += __shfl_xor(p, off);
        if (lane==0) alpha[(size_t)wid*H_ + h] = p;
    }
}

// ---- GAT segment softmax + aggregate, one block per dst node; dense alpha ----
__global__ __launch_bounds__(192) void k_segagg(bfp xlr, const float* __restrict__ alpha,
                         const void* gbias, size_t gbOff, const int* flagp, float* xf)
{
    __shared__ float al[12][6];
    __shared__ float w[12][6];
    const int f = *flagp;
    int node = blockIdx.x;
    int gl = node / A_, a = node % A_;
    int tid = threadIdx.x;
    if (tid < 72) ((float*)al)[tid] = alpha[(size_t)node*72 + tid];
    __syncthreads();
    if (tid < 6){
        float m = -1e30f;
        #pragma unroll
        for (int s=0;s<12;s++) m = fmaxf(m, al[s][tid]);
        float den = 0.f;
        #pragma unroll
        for (int s=0;s<12;s++){ float ex = expf(al[s][tid]-m); w[s][tid] = ex; den += ex; }
        float inv = 1.f/den;
        #pragma unroll
        for (int s=0;s<12;s++) w[s][tid] *= inv;
    }
    __syncthreads();
    int c = tid;
    float acc = 0.f;
    for (int s=0;s<12;s++){
        const bf16* xp = xlr + (size_t)(gl*A_ + s)*2304 + c;
        #pragma unroll
        for (int h=0;h<6;h++) acc += w[s][h]*b2f(xp[h*192]);
    }
    int b = gl / T_, t = gl % T_;
    int xrow = (b*A_ + a)*T_ + t;
    xf[(size_t)xrow*192 + c] += acc*(1.f/6.f) + ldf(gbias, gbOff + c, f);
}

__global__ __launch_bounds__(256) void k_store(const float* __restrict__ xf, void* out, const int* flagp)
{
    const int f = *flagp;
    int i = blockIdx.x*256 + threadIdx.x;
    if (i < ROWS_*192){
        if (f) ((bf16*)out)[1474560 + i] = __float2bfloat16(xf[i]);
        else   ((float*)out)[1474560 + i] = xf[i];
    }
}

extern "C" void kernel_launch(void* const* d_in, const int* in_sizes, int n_in,
                              void* d_out, int out_size, void* d_ws, size_t ws_size,
                              hipStream_t stream)
{
    const void* sf   = d_in[0];
    const int* ids  = (const int*)d_in[2];
    const int* eidx = (const int*)d_in[3];
    const void* ea   = d_in[4];
    const void* emb  = d_in[5];
    const void *laW1=d_in[6],  *lab1=d_in[7];
    const void *bn1g=d_in[8],  *bn1b=d_in[9],  *bn1m=d_in[10], *bn1v=d_in[11];
    const void *laW2=d_in[12], *lab2=d_in[13];
    const void *bn2g=d_in[14], *bn2b=d_in[15], *bn2m=d_in[16], *bn2v=d_in[17];
    const void *laW3=d_in[18], *lab3=d_in[19];
    const void *bn3g=d_in[20], *bn3b=d_in[21], *bn3m=d_in[22], *bn3v=d_in[23];
    const void *ln1g=d_in[24], *ln1b=d_in[25];
    const void *qkvw=d_in[26], *qkvb=d_in[27];
    const void *outw=d_in[28], *outb=d_in[29];
    const void *ln2g=d_in[30], *ln2b=d_in[31];
    const void *fw1 =d_in[32], *fb1 =d_in[33];
    const void *fw2 =d_in[34], *fb2 =d_in[35];
    const void *gwl =d_in[36], *gbl =d_in[37];
    const void *gwr =d_in[38], *gbr =d_in[39];
    const void *gwe =d_in[40];
    const void *gatt=d_in[41];
    const void *gbias=d_in[42];
    const void *ng  =d_in[43], *nb  =d_in[44];

    float* ws = (float*)d_ws;
    float* xf  = ws;                          // [0, 1474560)
    bf16*  xn  = (bf16*)(ws + 1474560);       // 1,474,560 bf16
    bf16*  qkv = (bf16*)(ws + 2211840);       // 4,423,680 bf16
    bf16*  ao  = (bf16*)(ws + 4423680);       // 1,474,560 bf16
    bf16*  hb  = (bf16*)(ws + 2211840);       // overlays qkv+ao (FFN hidden)
    bf16*  h2  = (bf16*)(ws + 2211840);       // overlays (MLP hidden)
    bf16*  xlr = (bf16*)(ws + 2211840);       // overlays (GAT full lr: 17,694,720 bf16)
    float* lea = ws + 11059200;               // 15,360
    int*  flag = (int*)(ws + 11074560);
    bf16*  WB  = (bf16*)(ws + 11074568);      // 2,731,136 bf16
    float* BB  = ws + 12440136;               // 12,608 f32
    float* alp = ws + 12452744;               // 552,960 f32 (dense [node][src][head])
    (void)ws_size; (void)in_sizes; (void)n_in; (void)out_size;

    k_detect<<<1, 1, 0, stream>>>(sf, flag);
    k_convert<<<(WB_TOT+BB_TOT+255)/256, 256, 0, stream>>>(
        qkvw, outw, fw1, fw2, gwl, gwr, gwe, gatt,
        laW1, lab1, bn1g, bn1b, bn1m, bn1v,
        laW2, lab2, bn2g, bn2b, bn2m, bn2v,
        laW3, lab3, bn3g, bn3b, bn3m, bn3v,
        qkvb, outb, fb1, fb2, gbl, gbr, flag, WB, BB);
    k_mlp_a<<<ROWS_/16, 256, 0, stream>>>(sf, ids, emb, flag, WB, BB, h2);
    k_mgemm<<<dim3(ROWS_/64, 3), 256, 0, stream>>>(h2, WB + WB_W3T, BB + BB_B3,
        nullptr, xf, nullptr, d_out, flag, 256, 192, 3);
    k_loopea<<<G_, 192, 0, stream>>>(eidx, ea, flag, lea);

    for (int l=0; l<3; l++){
        k_ln<<<ROWS_/4, 256, 0, stream>>>(xf, ln1g, ln1b, (size_t)l*192, flag, xn, 0);
        k_mgemm128<<<dim3(ROWS_/128, 9), 256, 0, stream>>>(xn, WB + WB_QKV + (size_t)l*110592,
            BB + BB_QKV + l*576, qkv, 192, 576, 0);
        k_attn<<<N_*H_*5, 64, 0, stream>>>(qkv, ao);
        k_mgemm<<<dim3(ROWS_/64, 3), 256, 0, stream>>>(ao, WB + WB_OUT + (size_t)l*36864,
            BB + BB_OUT + l*192, nullptr, xf, xf, nullptr, nullptr, 192, 192, 2);
        k_ln<<<ROWS_/4, 256, 0, stream>>>(xf, ln2g, ln2b, (size_t)l*192, flag, xn, 0);
        k_mgemm128<<<dim3(ROWS_/128, 12), 256, 0, stream>>>(xn, WB + WB_FW1 + (size_t)l*147456,
            BB + BB_FW1 + l*768, hb, 192, 768, 1);
        k_mgemm<<<dim3(ROWS_/64, 3), 256, 0, stream>>>(hb, WB + WB_FW2 + (size_t)l*147456,
            BB + BB_FW2 + l*192, nullptr, xf, xf, nullptr, nullptr, 768, 192, 2);
        k_ln<<<ROWS_/4, 256, 0, stream>>>(xf, ng, nb, (size_t)l*192, flag, xn, 1);
        k_mgemm128<<<dim3(ROWS_/128, 36), 256, 0, stream>>>(xn, WB + WB_GAT + (size_t)l*442368,
            BB + BB_GAT + l*2304, xlr, 192, 2304, 0);
        k_alpha<<<G_*144/4, 256, 0, stream>>>(xlr, lea, ea,
            WB + WB_GWE + (size_t)l*2304, WB + WB_GATT + (size_t)l*1152, flag, alp);
        k_segagg<<<G_*A_, 192, 0, stream>>>(xlr, alp, gbias, (size_t)l*192, flag, xf);
    }
    k_store<<<(ROWS_*192+255)/256, 256, 0, stream>>>(xf, d_out, flag);
}

// Round 12
// 870.389 us; speedup vs baseline: 1.4195x; 1.0574x over previous
//
#include <hip/hip_runtime.h>
#include <hip/hip_bf16.h>
#include <math.h>

#define A_   12
#define H_   6
#define N_   96
#define T_   80
#define G_   640
#define E_   132
#define E2_  144
#define ROWS_ 7680

typedef const __hip_bfloat16* bfp;
typedef __hip_bfloat16 bf16;
typedef __attribute__((ext_vector_type(8))) short short8;
typedef __attribute__((ext_vector_type(4))) short short4v;
typedef __attribute__((ext_vector_type(4))) float f32x4;
typedef _Float16 h2 __attribute__((ext_vector_type(2)));

// ---- bf16 weight arena element offsets (in 2-byte units) ----
#define WB_QKV   0                /* [3][576][192]  */
#define WB_OUT   331776           /* [3][192][192]  */
#define WB_FW1   442368           /* [3][768][192]  */
#define WB_FW2   884736           /* [3][192][768]  */
#define WB_GAT   1327104          /* [3][2304][192] (gwl|gwr) */
#define WB_W1    2654208          /* [16][64] BN-folded */
#define WB_W2    2655232          /* [64][256] BN-folded */
#define WB_W3T   2671616          /* [192][256] BN-folded, transposed */
#define WB_GWE   2720768          /* [3][2304]  (stored as fp16) */
#define WB_GATT  2727680          /* [3][1152]  (stored as fp16) */
#define WB_TOT   2731136
// ---- f32 bias arena element offsets ----
#define BB_QKV   0
#define BB_OUT   1728
#define BB_FW1   2304
#define BB_FW2   4608
#define BB_GAT   5184
#define BB_B1    12096
#define BB_B2    12160
#define BB_B3    12416
#define BB_TOT   12608

__device__ __forceinline__ float b2f(bf16 x){ return __bfloat162float(x); }
__device__ __forceinline__ float ldf(const void* p, size_t i, int f){
    return f ? __bfloat162float(((const bf16*)p)[i]) : ((const float*)p)[i];
}

// dtype probe: even uint16s of f32 storage are random mantissa halves.
__global__ void k_detect(const void* sf, int* flag)
{
    const unsigned short* u = (const unsigned short*)sf;
    int sane = 0;
    for (int i = 0; i < 64; i++){
        unsigned short v = u[2*i];
        int e = (v >> 7) & 0xFF;
        if (e == 0 || (e >= 100 && e <= 140)) sane++;
    }
    *flag = (sane >= 48) ? 1 : 0;
}

// ---- convert+transpose all weights into arena (bf16; gwe/gatt fp16); biases f32 ----
__global__ __launch_bounds__(256) void k_convert(
    const void* qkvw, const void* outw, const void* fw1, const void* fw2,
    const void* gwl, const void* gwr, const void* gwe, const void* gatt,
    const void* W1, const void* b1, const void* g1, const void* be1, const void* m1, const void* v1,
    const void* W2, const void* b2, const void* g2, const void* be2, const void* m2, const void* v2,
    const void* W3, const void* b3, const void* g3, const void* be3, const void* m3, const void* v3,
    const void* qkvb, const void* outb, const void* fb1, const void* fb2,
    const void* gbl, const void* gbr,
    const int* flagp, bf16* WB, float* BB)
{
    const int f = *flagp;
    size_t idx = (size_t)blockIdx.x*256 + threadIdx.x;
    if (idx < WB_TOT){
        float v; int ishalf = 0;
        if (idx < WB_OUT){            size_t i=idx-WB_QKV; int l=i/110592; int r=i%110592; int n=r/192, k=r%192;
            v = ldf(qkvw, (size_t)l*110592 + (size_t)k*576 + n, f);
        } else if (idx < WB_FW1){     size_t i=idx-WB_OUT; int l=i/36864; int r=i%36864; int n=r/192, k=r%192;
            v = ldf(outw, (size_t)l*36864 + (size_t)k*192 + n, f);
        } else if (idx < WB_FW2){     size_t i=idx-WB_FW1; int l=i/147456; int r=i%147456; int n=r/192, k=r%192;
            v = ldf(fw1, (size_t)l*147456 + (size_t)k*768 + n, f);
        } else if (idx < WB_GAT){     size_t i=idx-WB_FW2; int l=i/147456; int r=i%147456; int n=r/768, k=r%768;
            v = ldf(fw2, (size_t)l*147456 + (size_t)k*192 + n, f);
        } else if (idx < WB_W1){      size_t i=idx-WB_GAT; int l=i/442368; int r=i%442368; int n=r/192, k=r%192;
            if (n < 1152) v = ldf(gwl, (size_t)l*221184 + (size_t)k*1152 + n, f);
            else          v = ldf(gwr, (size_t)l*221184 + (size_t)k*1152 + (n-1152), f);
        } else if (idx < WB_W2){      size_t i=idx-WB_W1; int o=i%64;
            float s = ldf(g1,o,f)*rsqrtf(ldf(v1,o,f)+1e-5f);
            v = ldf(W1, i, f) * s;
        } else if (idx < WB_W3T){     size_t i=idx-WB_W2; int o=i%256;
            float s = ldf(g2,o,f)*rsqrtf(ldf(v2,o,f)+1e-5f);
            v = ldf(W2, i, f) * s;
        } else if (idx < WB_GWE){     size_t i=idx-WB_W3T; int n=i/256, k=i%256;
            float s = ldf(g3,n,f)*rsqrtf(ldf(v3,n,f)+1e-5f);
            v = ldf(W3, (size_t)k*192 + n, f) * s;
        } else if (idx < WB_GATT){    size_t i=idx-WB_GWE;
            v = ldf(gwe, i, f); ishalf = 1;
        } else {                      size_t i=idx-WB_GATT;
            v = ldf(gatt, i, f); ishalf = 1;
        }
        if (ishalf) ((_Float16*)WB)[idx] = (_Float16)v;
        else        WB[idx] = __float2bfloat16(v);
    } else if (idx < WB_TOT + BB_TOT){
        size_t j = idx - WB_TOT;
        float v;
        if (j < BB_OUT)        v = ldf(qkvb, j, f);
        else if (j < BB_FW1)   v = ldf(outb, j-BB_OUT, f);
        else if (j < BB_FW2)   v = ldf(fb1, j-BB_FW1, f);
        else if (j < BB_GAT)   v = ldf(fb2, j-BB_FW2, f);
        else if (j < BB_B1){   size_t i=j-BB_GAT; int l=i/2304; int o=i%2304;
            v = (o<1152) ? ldf(gbl, (size_t)l*1152+o, f) : ldf(gbr, (size_t)l*1152+o-1152, f);
        } else if (j < BB_B2){ int o=j-BB_B1;
            float s = ldf(g1,o,f)*rsqrtf(ldf(v1,o,f)+1e-5f);
            v = (ldf(b1,o,f)-ldf(m1,o,f))*s + ldf(be1,o,f);
        } else if (j < BB_B3){ int o=j-BB_B2;
            float s = ldf(g2,o,f)*rsqrtf(ldf(v2,o,f)+1e-5f);
            v = (ldf(b2,o,f)-ldf(m2,o,f))*s + ldf(be2,o,f);
        } else {               int o=j-BB_B3;
            float s = ldf(g3,o,f)*rsqrtf(ldf(v3,o,f)+1e-5f);
            v = (ldf(b3,o,f)-ldf(m3,o,f))*s + ldf(be3,o,f);
        }
        BB[j] = v;
    }
}

// ---- MLP stages 1+2: in16 -> 64 -> 256 (relu, BN folded), 16 rows/block ----
__global__ __launch_bounds__(256) void k_mlp_a(
    const void* sf, const int* ids, const void* emb, const int* flagp,
    const bf16* __restrict__ WB, const float* __restrict__ BB, bf16* h2g)
{
    __shared__ float in16[16][16];
    __shared__ float h1[16][64];
    const int f = *flagp;
    int tid = threadIdx.x;
    int row0 = blockIdx.x * 16;
    {
        int r = tid >> 4, i = tid & 15;
        int row = row0 + r;
        float v;
        if (i < 4) v = ldf(sf, (size_t)row*4 + i, f);
        else {
            int id = ids[row / T_]; if (id < 0) id = 0; if (id > 599) id = 599;
            v = ldf(emb, (size_t)id*12 + (i-4), f);
        }
        in16[r][i] = v;
    }
    __syncthreads();
    {
        int o = tid & 63, rg = tid >> 6;
        float acc[4];
        float bv = BB[BB_B1 + o];
        #pragma unroll
        for (int j=0;j<4;j++) acc[j] = bv;
        for (int i=0;i<16;i++){
            float w = b2f(WB[WB_W1 + i*64 + o]);
            #pragma unroll
            for (int j=0;j<4;j++) acc[j] += in16[rg*4+j][i]*w;
        }
        #pragma unroll
        for (int j=0;j<4;j++) h1[rg*4+j][o] = acc[j] > 0.f ? acc[j] : 0.f;
    }
    __syncthreads();
    {
        int o = tid;
        float acc[16];
        float bv = BB[BB_B2 + o];
        #pragma unroll
        for (int r=0;r<16;r++) acc[r] = bv;
        for (int i=0;i<64;i++){
            float w = b2f(WB[WB_W2 + i*256 + o]);
            #pragma unroll
            for (int r=0;r<16;r++) acc[r] += h1[r][i]*w;
        }
        for (int r=0;r<16;r++){
            float v = acc[r] > 0.f ? acc[r] : 0.f;
            h2g[(size_t)(row0+r)*256 + o] = __float2bfloat16(v);
        }
    }
}

// ---- MFMA GEMM (64x64 tile): C = A @ Wt^T + bias ----
// mode 0: bf16 store | 1: GELU bf16 | 2: outf = res + v | 3: relu -> out0(flag dtype) & xf = relu + PE
__global__ __launch_bounds__(256) void k_mgemm(
    const bf16* __restrict__ A, const bf16* __restrict__ Wt, const float* __restrict__ bias,
    bf16* outh, float* outf, const float* __restrict__ res, void* out0, const int* flagp,
    int K, int N, int mode)
{
    __shared__ short As[64*200];
    __shared__ short Bs[64*200];
    int tid = threadIdx.x;
    int w = tid >> 6, lane = tid & 63, q = lane >> 4, li = lane & 15;
    int m0 = blockIdx.x * 64, n0 = blockIdx.y * 64;
    const int f = flagp ? *flagp : 0;
    f32x4 acc[4];
    #pragma unroll
    for (int nt=0;nt<4;nt++) acc[nt] = (f32x4){0.f,0.f,0.f,0.f};
    int nkc = (K + 191) / 192;
    for (int kc = 0; kc < nkc; kc++){
        int kcw = K - kc*192; if (kcw > 192) kcw = 192;
        int vr = kcw >> 3;
        const bf16* Ab = A  + (size_t)m0*K + kc*192;
        const bf16* Bb = Wt + (size_t)n0*K + kc*192;
        for (int idx = tid; idx < 64*vr; idx += 256){
            int r = idx / vr, kv = idx - r*vr;
            *(short8*)&As[r*200 + kv*8] = *(const short8*)&Ab[(size_t)r*K + kv*8];
        }
        for (int idx = tid; idx < 64*vr; idx += 256){
            int r = idx / vr, kv = idx - r*vr;
            *(short8*)&Bs[r*200 + kv*8] = *(const short8*)&Bb[(size_t)r*K + kv*8];
        }
        __syncthreads();
        int kkn = kcw >> 5;
        for (int kk = 0; kk < kkn; kk++){
            int ko = kk*32 + q*8;
            short8 a = *(short8*)&As[(w*16+li)*200 + ko];
            #pragma unroll
            for (int nt = 0; nt < 4; nt++){
                short8 b = *(short8*)&Bs[(nt*16+li)*200 + ko];
                acc[nt] = __builtin_amdgcn_mfma_f32_16x16x32_bf16(a, b, acc[nt], 0, 0, 0);
            }
        }
        __syncthreads();
    }
    int rb = m0 + w*16 + q*4;
    #pragma unroll
    for (int nt = 0; nt < 4; nt++){
        int col = n0 + nt*16 + li;
        float bv = bias[col];
        #pragma unroll
        for (int p = 0; p < 4; p++){
            int row = rb + p;
            float v = acc[nt][p] + bv;
            size_t idx = (size_t)row*N + col;
            if (mode == 0) outh[idx] = __float2bfloat16(v);
            else if (mode == 1) outh[idx] = __float2bfloat16(0.5f*v*(1.f + erff(v*0.70710678118654752f)));
            else if (mode == 2) outf[idx] = v + res[idx];
            else {
                float r2 = v > 0.f ? v : 0.f;
                if (f) ((bf16*)out0)[idx] = __float2bfloat16(r2);
                else   ((float*)out0)[idx] = r2;
                int t = row % T_;
                int i2 = col & ~1;
                float dv = expf((float)i2 * (-9.210340371976184f/192.f));
                float ang = (float)t * dv;
                outf[idx] = r2 + ((col & 1) ? cosf(ang) : sinf(ang));
            }
        }
    }
}

// ---- MFMA GEMM (128x64 tile, K%96==0): mode 0 bf16 | 1 GELU bf16 | 4 fp16 ----
__global__ __launch_bounds__(256) void k_mgemm128(
    const bf16* __restrict__ A, const bf16* __restrict__ Wt, const float* __restrict__ bias,
    bf16* outh, int K, int N, int mode)
{
    __shared__ short As[128*104];
    __shared__ short Bs[64*104];
    int tid = threadIdx.x;
    int w = tid >> 6, lane = tid & 63, q = lane >> 4, li = lane & 15;
    int m0 = blockIdx.x * 128, n0 = blockIdx.y * 64;
    f32x4 acc[2][4];
    #pragma unroll
    for (int mt=0;mt<2;mt++)
        #pragma unroll
        for (int nt=0;nt<4;nt++) acc[mt][nt] = (f32x4){0.f,0.f,0.f,0.f};
    int nkc = K / 96;
    for (int kc = 0; kc < nkc; kc++){
        const bf16* Ab = A  + (size_t)m0*K + kc*96;
        const bf16* Bb = Wt + (size_t)n0*K + kc*96;
        for (int idx = tid; idx < 128*12; idx += 256){
            int r = idx / 12, kv = idx - r*12;
            *(short8*)&As[r*104 + kv*8] = *(const short8*)&Ab[(size_t)r*K + kv*8];
        }
        for (int idx = tid; idx < 64*12; idx += 256){
            int r = idx / 12, kv = idx - r*12;
            *(short8*)&Bs[r*104 + kv*8] = *(const short8*)&Bb[(size_t)r*K + kv*8];
        }
        __syncthreads();
        #pragma unroll
        for (int kk = 0; kk < 3; kk++){
            int ko = kk*32 + q*8;
            short8 b0 = *(short8*)&Bs[(0*16+li)*104 + ko];
            short8 b1 = *(short8*)&Bs[(1*16+li)*104 + ko];
            short8 b2 = *(short8*)&Bs[(2*16+li)*104 + ko];
            short8 b3 = *(short8*)&Bs[(3*16+li)*104 + ko];
            #pragma unroll
            for (int mt = 0; mt < 2; mt++){
                short8 a = *(short8*)&As[(w*32 + mt*16 + li)*104 + ko];
                acc[mt][0] = __builtin_amdgcn_mfma_f32_16x16x32_bf16(a, b0, acc[mt][0], 0, 0, 0);
                acc[mt][1] = __builtin_amdgcn_mfma_f32_16x16x32_bf16(a, b1, acc[mt][1], 0, 0, 0);
                acc[mt][2] = __builtin_amdgcn_mfma_f32_16x16x32_bf16(a, b2, acc[mt][2], 0, 0, 0);
                acc[mt][3] = __builtin_amdgcn_mfma_f32_16x16x32_bf16(a, b3, acc[mt][3], 0, 0, 0);
            }
        }
        __syncthreads();
    }
    #pragma unroll
    for (int mt = 0; mt < 2; mt++){
        int rb = m0 + w*32 + mt*16 + q*4;
        #pragma unroll
        for (int nt = 0; nt < 4; nt++){
            int col = n0 + nt*16 + li;
            float bv = bias[col];
            #pragma unroll
            for (int p = 0; p < 4; p++){
                float v = acc[mt][nt][p] + bv;
                size_t idx = (size_t)(rb+p)*N + col;
                if (mode == 0) outh[idx] = __float2bfloat16(v);
                else if (mode == 1) outh[idx] = __float2bfloat16(0.5f*v*(1.f + erff(v*0.70710678118654752f)));
                else ((_Float16*)outh)[idx] = (_Float16)v;
            }
        }
    }
}

// ---- LayerNorm (one wave per row), optional permute to node order ----
__global__ __launch_bounds__(256) void k_ln(const float* __restrict__ x, const void* g, const void* b,
                     size_t gOff, const int* flagp, bf16* out, int permute)
{
    const int f = *flagp;
    int tid = threadIdx.x;
    int row = blockIdx.x*4 + (tid>>6);
    int lane = tid & 63;
    const float* xr = x + (size_t)row*192;
    float v0 = xr[lane], v1 = xr[lane+64], v2 = xr[lane+128];
    float s = v0+v1+v2;
    float qq = v0*v0+v1*v1+v2*v2;
    #pragma unroll
    for (int off=32; off; off>>=1){ s += __shfl_xor(s, off); qq += __shfl_xor(qq, off); }
    float mean = s * (1.f/192.f);
    float var  = qq * (1.f/192.f) - mean*mean;
    float rs = rsqrtf(var + 1e-5f);
    int orow = row;
    if (permute){ int n = row/T_, t = row%T_; int bb = n/A_, a = n%A_; orow = (bb*T_+t)*A_ + a; }
    bf16* op = out + (size_t)orow*192;
    op[lane]     = __float2bfloat16((v0-mean)*rs*ldf(g,gOff+lane,f)     + ldf(b,gOff+lane,f));
    op[lane+64]  = __float2bfloat16((v1-mean)*rs*ldf(g,gOff+lane+64,f)  + ldf(b,gOff+lane+64,f));
    op[lane+128] = __float2bfloat16((v2-mean)*rs*ldf(g,gOff+lane+128,f) + ldf(b,gOff+lane+128,f));
}

// ---- causal attention, one wave per (seq, head, 16-query tile); online softmax ----
__global__ __launch_bounds__(64) void k_attn(bfp qkv, bf16* attn_o)
{
    __shared__ float Ks[80][32];
    __shared__ float Vs[80][32];
    int bid = blockIdx.x;
    int qt = bid % 5;
    int nh = bid / 5;
    int n = nh / H_, h = nh % H_;
    int tid = threadIdx.x;
    for (int idx = tid; idx < 640; idx += 64){
        int r = idx >> 3, c4 = (idx & 7) << 2;
        const bf16* rp = qkv + (size_t)(n*T_+r)*576 + h*32 + c4;
        short4v kv = *(const short4v*)(rp + 192);
        short4v vv = *(const short4v*)(rp + 384);
        f32x4 kf, vf;
        #pragma unroll
        for (int e=0;e<4;e++){
            kf[e] = __uint_as_float(((unsigned)(unsigned short)kv[e])<<16);
            vf[e] = __uint_as_float(((unsigned)(unsigned short)vv[e])<<16);
        }
        *(f32x4*)&Ks[r][c4] = kf;
        *(f32x4*)&Vs[r][c4] = vf;
    }
    __syncthreads();
    int qi = tid & 15, p = tid >> 4;
    int q = qt*16 + qi;
    float qv[8];
    const bf16* qp = qkv + (size_t)(n*T_+q)*576 + h*32 + p*8;
    #pragma unroll
    for (int c=0;c<8;c++) qv[c] = b2f(qp[c]);
    float m = -1e30f, l = 0.f;
    float acc[8];
    #pragma unroll
    for (int c=0;c<8;c++) acc[c]=0.f;
    int jmax = qt*16 + 15;
    for (int j = 0; j <= jmax; j++){
        float s = 0.f;
        #pragma unroll
        for (int c=0;c<8;c++) s += qv[c]*Ks[j][p*8+c];
        s += __shfl_xor(s, 16);
        s += __shfl_xor(s, 32);
        s *= 0.17677669529663687f;
        if (j > q) s = -1e30f;
        float mn = fmaxf(m, s);
        float corr = expf(m - mn);
        float e = expf(s - mn);
        l = l*corr + e;
        #pragma unroll
        for (int c=0;c<8;c++) acc[c] = acc[c]*corr + e*Vs[j][p*8+c];
        m = mn;
    }
    float inv = 1.f/l;
    bf16* op = attn_o + (size_t)(n*T_+q)*192 + h*32 + p*8;
    #pragma unroll
    for (int c=0;c<8;c++) op[c] = __float2bfloat16(acc[c]*inv);
}

// ---- self-loop attr = mean of incoming edge attrs; one block per graph ----
__global__ __launch_bounds__(192) void k_loopea(const int* __restrict__ eidx, const void* ea,
                                                const int* flagp, float* lea)
{
    __shared__ float s0[A_], s1[A_];
    __shared__ int cnt[A_];
    const int f = *flagp;
    int g = blockIdx.x;
    int tid = threadIdx.x;
    if (tid < A_){ s0[tid] = 0.f; s1[tid] = 0.f; cnt[tid] = 0; }
    __syncthreads();
    if (tid < E_){
        int d = eidx[E_ + tid];
        float a0 = ldf(ea, (size_t)(g*E_+tid)*2,   f);
        float a1 = ldf(ea, (size_t)(g*E_+tid)*2+1, f);
        atomicAdd(&s0[d], a0);
        atomicAdd(&s1[d], a1);
        atomicAdd(&cnt[d], 1);
    }
    __syncthreads();
    if (tid < A_){
        int c = cnt[tid] < 1 ? 1 : cnt[tid];
        lea[(g*A_+tid)*2]   = s0[tid]/(float)c;
        lea[(g*A_+tid)*2+1] = s1[tid]/(float)c;
    }
}

// ---- GAT edge logits: one wave per dense (g,d,s); fp16 packed math + v_dot2 ----
// alpha layout: [(g*12+d)*12 + s][H]. leaky(m) = 0.6*m + 0.4*|m|.
__global__ __launch_bounds__(256) void k_alpha(const _Float16* __restrict__ xlr,
                        const float* __restrict__ lea, const void* ea,
                        const _Float16* __restrict__ gweh, const _Float16* __restrict__ gatth,
                        const int* flagp, float* alpha)
{
    const int f = *flagp;
    int wid = blockIdx.x*4 + (threadIdx.x>>6);
    int lane = threadIdx.x & 63;
    int g = wid / 144, ds = wid % 144;
    int d = ds / 12, s = ds % 12;
    float f0, f1;
    if (s == d){
        f0 = lea[(g*A_+s)*2]; f1 = lea[(g*A_+s)*2+1];
    } else {
        int el = s*11 + (d < s ? d : d-1);
        f0 = ldf(ea, (size_t)(g*E_+el)*2,   f);
        f1 = ldf(ea, (size_t)(g*E_+el)*2+1, f);
    }
    h2 f0h = (h2){(_Float16)f0, (_Float16)f0};
    h2 f1h = (h2){(_Float16)f1, (_Float16)f1};
    const _Float16* xls = xlr + (size_t)(g*A_+s)*2304;
    const _Float16* xrd = xlr + (size_t)(g*A_+d)*2304 + 1152;
    int co = 6*lane;   // halves offset within a 2-head (384-ch) group
    #pragma unroll
    for (int hg = 0; hg < 3; hg++){
        int base = hg*384 + co;
        float pA = 0.f, pB = 0.f;
        #pragma unroll
        for (int j = 0; j < 3; j++){
            int o = base + 2*j;
            h2 xl2 = *(const h2*)(xls + o);
            h2 xr2 = *(const h2*)(xrd + o);
            h2 g0  = *(const h2*)(gweh + o);
            h2 g1  = *(const h2*)(gweh + 1152 + o);
            h2 ga  = *(const h2*)(gatth + o);
            h2 m = xl2 + xr2;
            m = g0*f0h + m;
            m = g1*f1h + m;
            unsigned mu = __builtin_bit_cast(unsigned, m) & 0x7fff7fffu;
            h2 am = __builtin_bit_cast(h2, mu);
            pA = __builtin_amdgcn_fdot2(ga, m,  pA, false);
            pB = __builtin_amdgcn_fdot2(ga, am, pB, false);
        }
        #pragma unroll
        for (int off=1; off<32; off<<=1){ pA += __shfl_xor(pA, off); pB += __shfl_xor(pB, off); }
        if ((lane & 31) == 0)
            alpha[(size_t)wid*H_ + hg*2 + (lane>>5)] = 0.6f*pA + 0.4f*pB;
    }
}

// ---- GAT segment softmax + aggregate, one block per dst node; dense alpha; fp16 xlr ----
__global__ __launch_bounds__(192) void k_segagg(const _Float16* __restrict__ xlr,
                         const float* __restrict__ alpha,
                         const void* gbias, size_t gbOff, const int* flagp, float* xf)
{
    __shared__ float al[12][6];
    __shared__ float w[12][6];
    const int f = *flagp;
    int node = blockIdx.x;
    int gl = node / A_, a = node % A_;
    int tid = threadIdx.x;
    if (tid < 72) ((float*)al)[tid] = alpha[(size_t)node*72 + tid];
    __syncthreads();
    if (tid < 6){
        float m = -1e30f;
        #pragma unroll
        for (int s=0;s<12;s++) m = fmaxf(m, al[s][tid]);
        float den = 0.f;
        #pragma unroll
        for (int s=0;s<12;s++){ float ex = expf(al[s][tid]-m); w[s][tid] = ex; den += ex; }
        float inv = 1.f/den;
        #pragma unroll
        for (int s=0;s<12;s++) w[s][tid] *= inv;
    }
    __syncthreads();
    int c = tid;
    float acc = 0.f;
    for (int s=0;s<12;s++){
        const _Float16* xp = xlr + (size_t)(gl*A_ + s)*2304 + c;
        #pragma unroll
        for (int h=0;h<6;h++) acc += w[s][h]*(float)xp[h*192];
    }
    int b = gl / T_, t = gl % T_;
    int xrow = (b*A_ + a)*T_ + t;
    xf[(size_t)xrow*192 + c] += acc*(1.f/6.f) + ldf(gbias, gbOff + c, f);
}

__global__ __launch_bounds__(256) void k_store(const float* __restrict__ xf, void* out, const int* flagp)
{
    const int f = *flagp;
    int i = blockIdx.x*256 + threadIdx.x;
    if (i < ROWS_*192){
        if (f) ((bf16*)out)[1474560 + i] = __float2bfloat16(xf[i]);
        else   ((float*)out)[1474560 + i] = xf[i];
    }
}

extern "C" void kernel_launch(void* const* d_in, const int* in_sizes, int n_in,
                              void* d_out, int out_size, void* d_ws, size_t ws_size,
                              hipStream_t stream)
{
    const void* sf   = d_in[0];
    const int* ids  = (const int*)d_in[2];
    const int* eidx = (const int*)d_in[3];
    const void* ea   = d_in[4];
    const void* emb  = d_in[5];
    const void *laW1=d_in[6],  *lab1=d_in[7];
    const void *bn1g=d_in[8],  *bn1b=d_in[9],  *bn1m=d_in[10], *bn1v=d_in[11];
    const void *laW2=d_in[12], *lab2=d_in[13];
    const void *bn2g=d_in[14], *bn2b=d_in[15], *bn2m=d_in[16], *bn2v=d_in[17];
    const void *laW3=d_in[18], *lab3=d_in[19];
    const void *bn3g=d_in[20], *bn3b=d_in[21], *bn3m=d_in[22], *bn3v=d_in[23];
    const void *ln1g=d_in[24], *ln1b=d_in[25];
    const void *qkvw=d_in[26], *qkvb=d_in[27];
    const void *outw=d_in[28], *outb=d_in[29];
    const void *ln2g=d_in[30], *ln2b=d_in[31];
    const void *fw1 =d_in[32], *fb1 =d_in[33];
    const void *fw2 =d_in[34], *fb2 =d_in[35];
    const void *gwl =d_in[36], *gbl =d_in[37];
    const void *gwr =d_in[38], *gbr =d_in[39];
    const void *gwe =d_in[40];
    const void *gatt=d_in[41];
    const void *gbias=d_in[42];
    const void *ng  =d_in[43], *nb  =d_in[44];

    float* ws = (float*)d_ws;
    float* xf  = ws;                          // [0, 1474560)
    bf16*  xn  = (bf16*)(ws + 1474560);       // 1,474,560 bf16
    bf16*  qkv = (bf16*)(ws + 2211840);       // 4,423,680 bf16
    bf16*  ao  = (bf16*)(ws + 4423680);       // 1,474,560 bf16
    bf16*  hb  = (bf16*)(ws + 2211840);       // overlays qkv+ao (FFN hidden)
    bf16*  h2g = (bf16*)(ws + 2211840);       // overlays (MLP hidden)
    bf16*  xlr = (bf16*)(ws + 2211840);       // overlays (GAT full lr: 17,694,720 fp16)
    float* lea = ws + 11059200;               // 15,360
    int*  flag = (int*)(ws + 11074560);
    bf16*  WB  = (bf16*)(ws + 11074568);      // 2,731,136 x 2B
    float* BB  = ws + 12440136;               // 12,608 f32
    float* alp = ws + 12452744;               // 552,960 f32 (dense [node][src][head])
    (void)ws_size; (void)in_sizes; (void)n_in; (void)out_size;

    k_detect<<<1, 1, 0, stream>>>(sf, flag);
    k_convert<<<(WB_TOT+BB_TOT+255)/256, 256, 0, stream>>>(
        qkvw, outw, fw1, fw2, gwl, gwr, gwe, gatt,
        laW1, lab1, bn1g, bn1b, bn1m, bn1v,
        laW2, lab2, bn2g, bn2b, bn2m, bn2v,
        laW3, lab3, bn3g, bn3b, bn3m, bn3v,
        qkvb, outb, fb1, fb2, gbl, gbr, flag, WB, BB);
    k_mlp_a<<<ROWS_/16, 256, 0, stream>>>(sf, ids, emb, flag, WB, BB, h2g);
    k_mgemm<<<dim3(ROWS_/64, 3), 256, 0, stream>>>(h2g, WB + WB_W3T, BB + BB_B3,
        nullptr, xf, nullptr, d_out, flag, 256, 192, 3);
    k_loopea<<<G_, 192, 0, stream>>>(eidx, ea, flag, lea);

    for (int l=0; l<3; l++){
        k_ln<<<ROWS_/4, 256, 0, stream>>>(xf, ln1g, ln1b, (size_t)l*192, flag, xn, 0);
        k_mgemm128<<<dim3(ROWS_/128, 9), 256, 0, stream>>>(xn, WB + WB_QKV + (size_t)l*110592,
            BB + BB_QKV + l*576, qkv, 192, 576, 0);
        k_attn<<<N_*H_*5, 64, 0, stream>>>(qkv, ao);
        k_mgemm<<<dim3(ROWS_/64, 3), 256, 0, stream>>>(ao, WB + WB_OUT + (size_t)l*36864,
            BB + BB_OUT + l*192, nullptr, xf, xf, nullptr, nullptr, 192, 192, 2);
        k_ln<<<ROWS_/4, 256, 0, stream>>>(xf, ln2g, ln2b, (size_t)l*192, flag, xn, 0);
        k_mgemm128<<<dim3(ROWS_/128, 12), 256, 0, stream>>>(xn, WB + WB_FW1 + (size_t)l*147456,
            BB + BB_FW1 + l*768, hb, 192, 768, 1);
        k_mgemm<<<dim3(ROWS_/64, 3), 256, 0, stream>>>(hb, WB + WB_FW2 + (size_t)l*147456,
            BB + BB_FW2 + l*192, nullptr, xf, xf, nullptr, nullptr, 768, 192, 2);
        k_ln<<<ROWS_/4, 256, 0, stream>>>(xf, ng, nb, (size_t)l*192, flag, xn, 1);
        k_mgemm128<<<dim3(ROWS_/128, 36), 256, 0, stream>>>(xn, WB + WB_GAT + (size_t)l*442368,
            BB + BB_GAT + l*2304, xlr, 192, 2304, 4);
        k_alpha<<<G_*144/4, 256, 0, stream>>>((const _Float16*)xlr, lea, ea,
            (const _Float16*)(WB + WB_GWE) + (size_t)l*2304,
            (const _Float16*)(WB + WB_GATT) + (size_t)l*1152, flag, alp);
        k_segagg<<<G_*A_, 192, 0, stream>>>((const _Float16*)xlr, alp, gbias, (size_t)l*192, flag, xf);
    }
    k_store<<<(ROWS_*192+255)/256, 256, 0, stream>>>(xf, d_out, flag);
}

// Round 13
// 857.675 us; speedup vs baseline: 1.4406x; 1.0148x over previous
//
#include <hip/hip_runtime.h>
#include <hip/hip_bf16.h>
#include <math.h>

#define A_   12
#define H_   6
#define N_   96
#define T_   80
#define G_   640
#define E_   132
#define E2_  144
#define ROWS_ 7680

typedef const __hip_bfloat16* bfp;
typedef __hip_bfloat16 bf16;
typedef __attribute__((ext_vector_type(8))) short short8;
typedef __attribute__((ext_vector_type(4))) short short4v;
typedef __attribute__((ext_vector_type(4))) float f32x4;
typedef _Float16 h2 __attribute__((ext_vector_type(2)));

// ---- bf16 weight arena element offsets (in 2-byte units) ----
#define WB_QKV   0                /* [3][576][192]  */
#define WB_OUT   331776           /* [3][192][192]  */
#define WB_FW1   442368           /* [3][768][192]  */
#define WB_FW2   884736           /* [3][192][768]  */
#define WB_GAT   1327104          /* [3][2304][192] (gwl|gwr) */
#define WB_W1    2654208          /* [16][64] BN-folded */
#define WB_W2    2655232          /* [64][256] BN-folded */
#define WB_W3T   2671616          /* [192][256] BN-folded, transposed */
#define WB_GWE   2720768          /* [3][2304]  (stored as fp16) */
#define WB_GATT  2727680          /* [3][1152]  (stored as fp16) */
#define WB_TOT   2731136
// ---- f32 bias arena element offsets ----
#define BB_QKV   0
#define BB_OUT   1728
#define BB_FW1   2304
#define BB_FW2   4608
#define BB_GAT   5184
#define BB_B1    12096
#define BB_B2    12160
#define BB_B3    12416
#define BB_TOT   12608

__device__ __forceinline__ float b2f(bf16 x){ return __bfloat162float(x); }
__device__ __forceinline__ float ldf(const void* p, size_t i, int f){
    return f ? __bfloat162float(((const bf16*)p)[i]) : ((const float*)p)[i];
}

// dtype probe: even uint16s of f32 storage are random mantissa halves.
__global__ void k_detect(const void* sf, int* flag)
{
    const unsigned short* u = (const unsigned short*)sf;
    int sane = 0;
    for (int i = 0; i < 64; i++){
        unsigned short v = u[2*i];
        int e = (v >> 7) & 0xFF;
        if (e == 0 || (e >= 100 && e <= 140)) sane++;
    }
    *flag = (sane >= 48) ? 1 : 0;
}

// ---- convert+transpose all weights into arena (bf16; gwe/gatt fp16); biases f32 ----
__global__ __launch_bounds__(256) void k_convert(
    const void* qkvw, const void* outw, const void* fw1, const void* fw2,
    const void* gwl, const void* gwr, const void* gwe, const void* gatt,
    const void* W1, const void* b1, const void* g1, const void* be1, const void* m1, const void* v1,
    const void* W2, const void* b2, const void* g2, const void* be2, const void* m2, const void* v2,
    const void* W3, const void* b3, const void* g3, const void* be3, const void* m3, const void* v3,
    const void* qkvb, const void* outb, const void* fb1, const void* fb2,
    const void* gbl, const void* gbr,
    const int* flagp, bf16* WB, float* BB)
{
    const int f = *flagp;
    size_t idx = (size_t)blockIdx.x*256 + threadIdx.x;
    if (idx < WB_TOT){
        float v; int ishalf = 0;
        if (idx < WB_OUT){            size_t i=idx-WB_QKV; int l=i/110592; int r=i%110592; int n=r/192, k=r%192;
            v = ldf(qkvw, (size_t)l*110592 + (size_t)k*576 + n, f);
        } else if (idx < WB_FW1){     size_t i=idx-WB_OUT; int l=i/36864; int r=i%36864; int n=r/192, k=r%192;
            v = ldf(outw, (size_t)l*36864 + (size_t)k*192 + n, f);
        } else if (idx < WB_FW2){     size_t i=idx-WB_FW1; int l=i/147456; int r=i%147456; int n=r/192, k=r%192;
            v = ldf(fw1, (size_t)l*147456 + (size_t)k*768 + n, f);
        } else if (idx < WB_GAT){     size_t i=idx-WB_FW2; int l=i/147456; int r=i%147456; int n=r/768, k=r%768;
            v = ldf(fw2, (size_t)l*147456 + (size_t)k*192 + n, f);
        } else if (idx < WB_W1){      size_t i=idx-WB_GAT; int l=i/442368; int r=i%442368; int n=r/192, k=r%192;
            if (n < 1152) v = ldf(gwl, (size_t)l*221184 + (size_t)k*1152 + n, f);
            else          v = ldf(gwr, (size_t)l*221184 + (size_t)k*1152 + (n-1152), f);
        } else if (idx < WB_W2){      size_t i=idx-WB_W1; int o=i%64;
            float s = ldf(g1,o,f)*rsqrtf(ldf(v1,o,f)+1e-5f);
            v = ldf(W1, i, f) * s;
        } else if (idx < WB_W3T){     size_t i=idx-WB_W2; int o=i%256;
            float s = ldf(g2,o,f)*rsqrtf(ldf(v2,o,f)+1e-5f);
            v = ldf(W2, i, f) * s;
        } else if (idx < WB_GWE){     size_t i=idx-WB_W3T; int n=i/256, k=i%256;
            float s = ldf(g3,n,f)*rsqrtf(ldf(v3,n,f)+1e-5f);
            v = ldf(W3, (size_t)k*192 + n, f) * s;
        } else if (idx < WB_GATT){    size_t i=idx-WB_GWE;
            v = ldf(gwe, i, f); ishalf = 1;
        } else {                      size_t i=idx-WB_GATT;
            v = ldf(gatt, i, f); ishalf = 1;
        }
        if (ishalf) ((_Float16*)WB)[idx] = (_Float16)v;
        else        WB[idx] = __float2bfloat16(v);
    } else if (idx < WB_TOT + BB_TOT){
        size_t j = idx - WB_TOT;
        float v;
        if (j < BB_OUT)        v = ldf(qkvb, j, f);
        else if (j < BB_FW1)   v = ldf(outb, j-BB_OUT, f);
        else if (j < BB_FW2)   v = ldf(fb1, j-BB_FW1, f);
        else if (j < BB_GAT)   v = ldf(fb2, j-BB_FW2, f);
        else if (j < BB_B1){   size_t i=j-BB_GAT; int l=i/2304; int o=i%2304;
            v = (o<1152) ? ldf(gbl, (size_t)l*1152+o, f) : ldf(gbr, (size_t)l*1152+o-1152, f);
        } else if (j < BB_B2){ int o=j-BB_B1;
            float s = ldf(g1,o,f)*rsqrtf(ldf(v1,o,f)+1e-5f);
            v = (ldf(b1,o,f)-ldf(m1,o,f))*s + ldf(be1,o,f);
        } else if (j < BB_B3){ int o=j-BB_B2;
            float s = ldf(g2,o,f)*rsqrtf(ldf(v2,o,f)+1e-5f);
            v = (ldf(b2,o,f)-ldf(m2,o,f))*s + ldf(be2,o,f);
        } else {               int o=j-BB_B3;
            float s = ldf(g3,o,f)*rsqrtf(ldf(v3,o,f)+1e-5f);
            v = (ldf(b3,o,f)-ldf(m3,o,f))*s + ldf(be3,o,f);
        }
        BB[j] = v;
    }
}

// ---- MLP stages 1+2: in16 -> 64 -> 256 (relu, BN folded), 16 rows/block ----
__global__ __launch_bounds__(256) void k_mlp_a(
    const void* sf, const int* ids, const void* emb, const int* flagp,
    const bf16* __restrict__ WB, const float* __restrict__ BB, bf16* h2g)
{
    __shared__ float in16[16][16];
    __shared__ float h1[16][64];
    const int f = *flagp;
    int tid = threadIdx.x;
    int row0 = blockIdx.x * 16;
    {
        int r = tid >> 4, i = tid & 15;
        int row = row0 + r;
        float v;
        if (i < 4) v = ldf(sf, (size_t)row*4 + i, f);
        else {
            int id = ids[row / T_]; if (id < 0) id = 0; if (id > 599) id = 599;
            v = ldf(emb, (size_t)id*12 + (i-4), f);
        }
        in16[r][i] = v;
    }
    __syncthreads();
    {
        int o = tid & 63, rg = tid >> 6;
        float acc[4];
        float bv = BB[BB_B1 + o];
        #pragma unroll
        for (int j=0;j<4;j++) acc[j] = bv;
        for (int i=0;i<16;i++){
            float w = b2f(WB[WB_W1 + i*64 + o]);
            #pragma unroll
            for (int j=0;j<4;j++) acc[j] += in16[rg*4+j][i]*w;
        }
        #pragma unroll
        for (int j=0;j<4;j++) h1[rg*4+j][o] = acc[j] > 0.f ? acc[j] : 0.f;
    }
    __syncthreads();
    {
        int o = tid;
        float acc[16];
        float bv = BB[BB_B2 + o];
        #pragma unroll
        for (int r=0;r<16;r++) acc[r] = bv;
        for (int i=0;i<64;i++){
            float w = b2f(WB[WB_W2 + i*256 + o]);
            #pragma unroll
            for (int r=0;r<16;r++) acc[r] += h1[r][i]*w;
        }
        for (int r=0;r<16;r++){
            float v = acc[r] > 0.f ? acc[r] : 0.f;
            h2g[(size_t)(row0+r)*256 + o] = __float2bfloat16(v);
        }
    }
}

// ---- MFMA GEMM (64x64 tile): C = A @ Wt^T + bias ----
// mode 0: bf16 store | 1: GELU bf16 | 2: outf = res + v | 3: relu -> out0(flag dtype) & xf = relu + PE
__global__ __launch_bounds__(256) void k_mgemm(
    const bf16* __restrict__ A, const bf16* __restrict__ Wt, const float* __restrict__ bias,
    bf16* outh, float* outf, const float* __restrict__ res, void* out0, const int* flagp,
    int K, int N, int mode)
{
    __shared__ short As[64*200];
    __shared__ short Bs[64*200];
    int tid = threadIdx.x;
    int w = tid >> 6, lane = tid & 63, q = lane >> 4, li = lane & 15;
    int m0 = blockIdx.x * 64, n0 = blockIdx.y * 64;
    const int f = flagp ? *flagp : 0;
    f32x4 acc[4];
    #pragma unroll
    for (int nt=0;nt<4;nt++) acc[nt] = (f32x4){0.f,0.f,0.f,0.f};
    int nkc = (K + 191) / 192;
    for (int kc = 0; kc < nkc; kc++){
        int kcw = K - kc*192; if (kcw > 192) kcw = 192;
        int vr = kcw >> 3;
        const bf16* Ab = A  + (size_t)m0*K + kc*192;
        const bf16* Bb = Wt + (size_t)n0*K + kc*192;
        for (int idx = tid; idx < 64*vr; idx += 256){
            int r = idx / vr, kv = idx - r*vr;
            *(short8*)&As[r*200 + kv*8] = *(const short8*)&Ab[(size_t)r*K + kv*8];
        }
        for (int idx = tid; idx < 64*vr; idx += 256){
            int r = idx / vr, kv = idx - r*vr;
            *(short8*)&Bs[r*200 + kv*8] = *(const short8*)&Bb[(size_t)r*K + kv*8];
        }
        __syncthreads();
        int kkn = kcw >> 5;
        for (int kk = 0; kk < kkn; kk++){
            int ko = kk*32 + q*8;
            short8 a = *(short8*)&As[(w*16+li)*200 + ko];
            #pragma unroll
            for (int nt = 0; nt < 4; nt++){
                short8 b = *(short8*)&Bs[(nt*16+li)*200 + ko];
                acc[nt] = __builtin_amdgcn_mfma_f32_16x16x32_bf16(a, b, acc[nt], 0, 0, 0);
            }
        }
        __syncthreads();
    }
    int rb = m0 + w*16 + q*4;
    #pragma unroll
    for (int nt = 0; nt < 4; nt++){
        int col = n0 + nt*16 + li;
        float bv = bias[col];
        #pragma unroll
        for (int p = 0; p < 4; p++){
            int row = rb + p;
            float v = acc[nt][p] + bv;
            size_t idx = (size_t)row*N + col;
            if (mode == 0) outh[idx] = __float2bfloat16(v);
            else if (mode == 1) outh[idx] = __float2bfloat16(0.5f*v*(1.f + erff(v*0.70710678118654752f)));
            else if (mode == 2) outf[idx] = v + res[idx];
            else {
                float r2 = v > 0.f ? v : 0.f;
                if (f) ((bf16*)out0)[idx] = __float2bfloat16(r2);
                else   ((float*)out0)[idx] = r2;
                int t = row % T_;
                int i2 = col & ~1;
                float dv = expf((float)i2 * (-9.210340371976184f/192.f));
                float ang = (float)t * dv;
                outf[idx] = r2 + ((col & 1) ? cosf(ang) : sinf(ang));
            }
        }
    }
}

// ---- MFMA GEMM (128x64 tile, K%96==0): mode 0 bf16 | 1 GELU bf16 | 4 fp16 ----
__global__ __launch_bounds__(256) void k_mgemm128(
    const bf16* __restrict__ A, const bf16* __restrict__ Wt, const float* __restrict__ bias,
    bf16* outh, int K, int N, int mode)
{
    __shared__ short As[128*104];
    __shared__ short Bs[64*104];
    int tid = threadIdx.x;
    int w = tid >> 6, lane = tid & 63, q = lane >> 4, li = lane & 15;
    int m0 = blockIdx.x * 128, n0 = blockIdx.y * 64;
    f32x4 acc[2][4];
    #pragma unroll
    for (int mt=0;mt<2;mt++)
        #pragma unroll
        for (int nt=0;nt<4;nt++) acc[mt][nt] = (f32x4){0.f,0.f,0.f,0.f};
    int nkc = K / 96;
    for (int kc = 0; kc < nkc; kc++){
        const bf16* Ab = A  + (size_t)m0*K + kc*96;
        const bf16* Bb = Wt + (size_t)n0*K + kc*96;
        for (int idx = tid; idx < 128*12; idx += 256){
            int r = idx / 12, kv = idx - r*12;
            *(short8*)&As[r*104 + kv*8] = *(const short8*)&Ab[(size_t)r*K + kv*8];
        }
        for (int idx = tid; idx < 64*12; idx += 256){
            int r = idx / 12, kv = idx - r*12;
            *(short8*)&Bs[r*104 + kv*8] = *(const short8*)&Bb[(size_t)r*K + kv*8];
        }
        __syncthreads();
        #pragma unroll
        for (int kk = 0; kk < 3; kk++){
            int ko = kk*32 + q*8;
            short8 b0 = *(short8*)&Bs[(0*16+li)*104 + ko];
            short8 b1 = *(short8*)&Bs[(1*16+li)*104 + ko];
            short8 b2 = *(short8*)&Bs[(2*16+li)*104 + ko];
            short8 b3 = *(short8*)&Bs[(3*16+li)*104 + ko];
            #pragma unroll
            for (int mt = 0; mt < 2; mt++){
                short8 a = *(short8*)&As[(w*32 + mt*16 + li)*104 + ko];
                acc[mt][0] = __builtin_amdgcn_mfma_f32_16x16x32_bf16(a, b0, acc[mt][0], 0, 0, 0);
                acc[mt][1] = __builtin_amdgcn_mfma_f32_16x16x32_bf16(a, b1, acc[mt][1], 0, 0, 0);
                acc[mt][2] = __builtin_amdgcn_mfma_f32_16x16x32_bf16(a, b2, acc[mt][2], 0, 0, 0);
                acc[mt][3] = __builtin_amdgcn_mfma_f32_16x16x32_bf16(a, b3, acc[mt][3], 0, 0, 0);
            }
        }
        __syncthreads();
    }
    #pragma unroll
    for (int mt = 0; mt < 2; mt++){
        int rb = m0 + w*32 + mt*16 + q*4;
        #pragma unroll
        for (int nt = 0; nt < 4; nt++){
            int col = n0 + nt*16 + li;
            float bv = bias[col];
            #pragma unroll
            for (int p = 0; p < 4; p++){
                float v = acc[mt][nt][p] + bv;
                size_t idx = (size_t)(rb+p)*N + col;
                if (mode == 0) outh[idx] = __float2bfloat16(v);
                else if (mode == 1) outh[idx] = __float2bfloat16(0.5f*v*(1.f + erff(v*0.70710678118654752f)));
                else ((_Float16*)outh)[idx] = (_Float16)v;
            }
        }
    }
}

// ---- LayerNorm (one wave per row), optional permute to node order ----
__global__ __launch_bounds__(256) void k_ln(const float* __restrict__ x, const void* g, const void* b,
                     size_t gOff, const int* flagp, bf16* out, int permute)
{
    const int f = *flagp;
    int tid = threadIdx.x;
    int row = blockIdx.x*4 + (tid>>6);
    int lane = tid & 63;
    const float* xr = x + (size_t)row*192;
    float v0 = xr[lane], v1 = xr[lane+64], v2 = xr[lane+128];
    float s = v0+v1+v2;
    float qq = v0*v0+v1*v1+v2*v2;
    #pragma unroll
    for (int off=32; off; off>>=1){ s += __shfl_xor(s, off); qq += __shfl_xor(qq, off); }
    float mean = s * (1.f/192.f);
    float var  = qq * (1.f/192.f) - mean*mean;
    float rs = rsqrtf(var + 1e-5f);
    int orow = row;
    if (permute){ int n = row/T_, t = row%T_; int bb = n/A_, a = n%A_; orow = (bb*T_+t)*A_ + a; }
    bf16* op = out + (size_t)orow*192;
    op[lane]     = __float2bfloat16((v0-mean)*rs*ldf(g,gOff+lane,f)     + ldf(b,gOff+lane,f));
    op[lane+64]  = __float2bfloat16((v1-mean)*rs*ldf(g,gOff+lane+64,f)  + ldf(b,gOff+lane+64,f));
    op[lane+128] = __float2bfloat16((v2-mean)*rs*ldf(g,gOff+lane+128,f) + ldf(b,gOff+lane+128,f));
}

// ---- causal attention, one wave per (seq, head, 16-query tile); online softmax ----
__global__ __launch_bounds__(64) void k_attn(bfp qkv, bf16* attn_o)
{
    __shared__ float Ks[80][32];
    __shared__ float Vs[80][32];
    int bid = blockIdx.x;
    int qt = bid % 5;
    int nh = bid / 5;
    int n = nh / H_, h = nh % H_;
    int tid = threadIdx.x;
    for (int idx = tid; idx < 640; idx += 64){
        int r = idx >> 3, c4 = (idx & 7) << 2;
        const bf16* rp = qkv + (size_t)(n*T_+r)*576 + h*32 + c4;
        short4v kv = *(const short4v*)(rp + 192);
        short4v vv = *(const short4v*)(rp + 384);
        f32x4 kf, vf;
        #pragma unroll
        for (int e=0;e<4;e++){
            kf[e] = __uint_as_float(((unsigned)(unsigned short)kv[e])<<16);
            vf[e] = __uint_as_float(((unsigned)(unsigned short)vv[e])<<16);
        }
        *(f32x4*)&Ks[r][c4] = kf;
        *(f32x4*)&Vs[r][c4] = vf;
    }
    __syncthreads();
    int qi = tid & 15, p = tid >> 4;
    int q = qt*16 + qi;
    float qv[8];
    const bf16* qp = qkv + (size_t)(n*T_+q)*576 + h*32 + p*8;
    #pragma unroll
    for (int c=0;c<8;c++) qv[c] = b2f(qp[c]);
    float m = -1e30f, l = 0.f;
    float acc[8];
    #pragma unroll
    for (int c=0;c<8;c++) acc[c]=0.f;
    int jmax = qt*16 + 15;
    for (int j = 0; j <= jmax; j++){
        float s = 0.f;
        #pragma unroll
        for (int c=0;c<8;c++) s += qv[c]*Ks[j][p*8+c];
        s += __shfl_xor(s, 16);
        s += __shfl_xor(s, 32);
        s *= 0.17677669529663687f;
        if (j > q) s = -1e30f;
        float mn = fmaxf(m, s);
        float corr = expf(m - mn);
        float e = expf(s - mn);
        l = l*corr + e;
        #pragma unroll
        for (int c=0;c<8;c++) acc[c] = acc[c]*corr + e*Vs[j][p*8+c];
        m = mn;
    }
    float inv = 1.f/l;
    bf16* op = attn_o + (size_t)(n*T_+q)*192 + h*32 + p*8;
    #pragma unroll
    for (int c=0;c<8;c++) op[c] = __float2bfloat16(acc[c]*inv);
}

// ---- self-loop attr = mean of incoming edge attrs; one block per graph ----
__global__ __launch_bounds__(192) void k_loopea(const int* __restrict__ eidx, const void* ea,
                                                const int* flagp, float* lea)
{
    __shared__ float s0[A_], s1[A_];
    __shared__ int cnt[A_];
    const int f = *flagp;
    int g = blockIdx.x;
    int tid = threadIdx.x;
    if (tid < A_){ s0[tid] = 0.f; s1[tid] = 0.f; cnt[tid] = 0; }
    __syncthreads();
    if (tid < E_){
        int d = eidx[E_ + tid];
        float a0 = ldf(ea, (size_t)(g*E_+tid)*2,   f);
        float a1 = ldf(ea, (size_t)(g*E_+tid)*2+1, f);
        atomicAdd(&s0[d], a0);
        atomicAdd(&s1[d], a1);
        atomicAdd(&cnt[d], 1);
    }
    __syncthreads();
    if (tid < A_){
        int c = cnt[tid] < 1 ? 1 : cnt[tid];
        lea[(g*A_+tid)*2]   = s0[tid]/(float)c;
        lea[(g*A_+tid)*2+1] = s1[tid]/(float)c;
    }
}

// ---- GAT edge logits: one wave per dense (g,d,s); fp16 packed + fused leaky dot.
// XCD-swizzled: all 36 blocks of a graph land on one XCD (g = (bid&7)*80 + ...).
// alpha layout: [(g*12+d)*12 + s][H].
__global__ __launch_bounds__(256) void k_alpha(const _Float16* __restrict__ xlr,
                        const float* __restrict__ lea, const void* ea,
                        const _Float16* __restrict__ gweh, const _Float16* __restrict__ gatth,
                        const int* flagp, float* alpha)
{
    const int f = *flagp;
    int bid = blockIdx.x;
    int xcd = bid & 7, slot = bid >> 3;          // 2880 slots; 360 per XCD
    int g = xcd*80 + slot/36;                    // 80 graphs per XCD
    int ds = (slot % 36)*4 + (threadIdx.x>>6);   // 0..143
    int lane = threadIdx.x & 63;
    int d = ds / 12, s = ds % 12;
    float f0, f1;
    if (s == d){
        f0 = lea[(g*A_+s)*2]; f1 = lea[(g*A_+s)*2+1];
    } else {
        int el = s*11 + (d < s ? d : d-1);
        f0 = ldf(ea, (size_t)(g*E_+el)*2,   f);
        f1 = ldf(ea, (size_t)(g*E_+el)*2+1, f);
    }
    h2 f0h = (h2){(_Float16)f0, (_Float16)f0};
    h2 f1h = (h2){(_Float16)f1, (_Float16)f1};
    const h2 c06 = (h2){(_Float16)0.6f, (_Float16)0.6f};
    const h2 c04 = (h2){(_Float16)0.4f, (_Float16)0.4f};
    const _Float16* xls = xlr + (size_t)(g*A_+s)*2304;
    const _Float16* xrd = xlr + (size_t)(g*A_+d)*2304 + 1152;
    int co = 6*lane;
    #pragma unroll
    for (int hg = 0; hg < 3; hg++){
        int base = hg*384 + co;
        float p = 0.f;
        #pragma unroll
        for (int j = 0; j < 3; j++){
            int o = base + 2*j;
            h2 xl2 = *(const h2*)(xls + o);
            h2 xr2 = *(const h2*)(xrd + o);
            h2 g0  = *(const h2*)(gweh + o);
            h2 g1  = *(const h2*)(gweh + 1152 + o);
            h2 ga  = *(const h2*)(gatth + o);
            h2 m = xl2 + xr2;
            m = g0*f0h + m;
            m = g1*f1h + m;
            unsigned mu = __builtin_bit_cast(unsigned, m) & 0x7fff7fffu;
            h2 am = __builtin_bit_cast(h2, mu);
            h2 q = m*c06 + am*c04;               // leaky(m), slope 0.2
            p = __builtin_amdgcn_fdot2(ga, q, p, false);
        }
        #pragma unroll
        for (int off=1; off<32; off<<=1) p += __shfl_xor(p, off);
        if ((lane & 31) == 0)
            alpha[((size_t)(g*A_+d)*12 + s)*H_ + hg*2 + (lane>>5)] = p;
    }
}

// ---- GAT segment softmax + aggregate; XCD-swizzled (12 node-blocks/graph on one XCD) ----
__global__ __launch_bounds__(192) void k_segagg(const _Float16* __restrict__ xlr,
                         const float* __restrict__ alpha,
                         const void* gbias, size_t gbOff, const int* flagp, float* xf)
{
    __shared__ float al[12][6];
    __shared__ float w[12][6];
    const int f = *flagp;
    int bid = blockIdx.x;
    int xcd = bid & 7, slot = bid >> 3;          // 960 slots; 120 per XCD
    int gl = xcd*80 + slot/12;
    int a = slot % 12;
    int node = gl*A_ + a;
    int tid = threadIdx.x;
    if (tid < 72) ((float*)al)[tid] = alpha[(size_t)node*72 + tid];
    __syncthreads();
    if (tid < 6){
        float m = -1e30f;
        #pragma unroll
        for (int s=0;s<12;s++) m = fmaxf(m, al[s][tid]);
        float den = 0.f;
        #pragma unroll
        for (int s=0;s<12;s++){ float ex = expf(al[s][tid]-m); w[s][tid] = ex; den += ex; }
        float inv = 1.f/den;
        #pragma unroll
        for (int s=0;s<12;s++) w[s][tid] *= inv;
    }
    __syncthreads();
    int c = tid;
    float acc = 0.f;
    for (int s=0;s<12;s++){
        const _Float16* xp = xlr + (size_t)(gl*A_ + s)*2304 + c;
        #pragma unroll
        for (int h=0;h<6;h++) acc += w[s][h]*(float)xp[h*192];
    }
    int b = gl / T_, t = gl % T_;
    int xrow = (b*A_ + a)*T_ + t;
    xf[(size_t)xrow*192 + c] += acc*(1.f/6.f) + ldf(gbias, gbOff + c, f);
}

__global__ __launch_bounds__(256) void k_store(const float* __restrict__ xf, void* out, const int* flagp)
{
    const int f = *flagp;
    int i = blockIdx.x*256 + threadIdx.x;
    if (i < ROWS_*192){
        if (f) ((bf16*)out)[1474560 + i] = __float2bfloat16(xf[i]);
        else   ((float*)out)[1474560 + i] = xf[i];
    }
}

extern "C" void kernel_launch(void* const* d_in, const int* in_sizes, int n_in,
                              void* d_out, int out_size, void* d_ws, size_t ws_size,
                              hipStream_t stream)
{
    const void* sf   = d_in[0];
    const int* ids  = (const int*)d_in[2];
    const int* eidx = (const int*)d_in[3];
    const void* ea   = d_in[4];
    const void* emb  = d_in[5];
    const void *laW1=d_in[6],  *lab1=d_in[7];
    const void *bn1g=d_in[8],  *bn1b=d_in[9],  *bn1m=d_in[10], *bn1v=d_in[11];
    const void *laW2=d_in[12], *lab2=d_in[13];
    const void *bn2g=d_in[14], *bn2b=d_in[15], *bn2m=d_in[16], *bn2v=d_in[17];
    const void *laW3=d_in[18], *lab3=d_in[19];
    const void *bn3g=d_in[20], *bn3b=d_in[21], *bn3m=d_in[22], *bn3v=d_in[23];
    const void *ln1g=d_in[24], *ln1b=d_in[25];
    const void *qkvw=d_in[26], *qkvb=d_in[27];
    const void *outw=d_in[28], *outb=d_in[29];
    const void *ln2g=d_in[30], *ln2b=d_in[31];
    const void *fw1 =d_in[32], *fb1 =d_in[33];
    const void *fw2 =d_in[34], *fb2 =d_in[35];
    const void *gwl =d_in[36], *gbl =d_in[37];
    const void *gwr =d_in[38], *gbr =d_in[39];
    const void *gwe =d_in[40];
    const void *gatt=d_in[41];
    const void *gbias=d_in[42];
    const void *ng  =d_in[43], *nb  =d_in[44];

    float* ws = (float*)d_ws;
    float* xf  = ws;                          // [0, 1474560)
    bf16*  xn  = (bf16*)(ws + 1474560);       // 1,474,560 bf16
    bf16*  qkv = (bf16*)(ws + 2211840);       // 4,423,680 bf16
    bf16*  ao  = (bf16*)(ws + 4423680);       // 1,474,560 bf16
    bf16*  hb  = (bf16*)(ws + 2211840);       // overlays qkv+ao (FFN hidden)
    bf16*  h2g = (bf16*)(ws + 2211840);       // overlays (MLP hidden)
    bf16*  xlr = (bf16*)(ws + 2211840);       // overlays (GAT full lr: 17,694,720 fp16)
    float* lea = ws + 11059200;               // 15,360
    int*  flag = (int*)(ws + 11074560);
    bf16*  WB  = (bf16*)(ws + 11074568);      // 2,731,136 x 2B
    float* BB  = ws + 12440136;               // 12,608 f32
    float* alp = ws + 12452744;               // 552,960 f32 (dense [node][src][head])
    (void)ws_size; (void)in_sizes; (void)n_in; (void)out_size;

    k_detect<<<1, 1, 0, stream>>>(sf, flag);
    k_convert<<<(WB_TOT+BB_TOT+255)/256, 256, 0, stream>>>(
        qkvw, outw, fw1, fw2, gwl, gwr, gwe, gatt,
        laW1, lab1, bn1g, bn1b, bn1m, bn1v,
        laW2, lab2, bn2g, bn2b, bn2m, bn2v,
        laW3, lab3, bn3g, bn3b, bn3m, bn3v,
        qkvb, outb, fb1, fb2, gbl, gbr, flag, WB, BB);
    k_mlp_a<<<ROWS_/16, 256, 0, stream>>>(sf, ids, emb, flag, WB, BB, h2g);
    k_mgemm<<<dim3(ROWS_/64, 3), 256, 0, stream>>>(h2g, WB + WB_W3T, BB + BB_B3,
        nullptr, xf, nullptr, d_out, flag, 256, 192, 3);
    k_loopea<<<G_, 192, 0, stream>>>(eidx, ea, flag, lea);

    for (int l=0; l<3; l++){
        k_ln<<<ROWS_/4, 256, 0, stream>>>(xf, ln1g, ln1b, (size_t)l*192, flag, xn, 0);
        k_mgemm128<<<dim3(ROWS_/128, 9), 256, 0, stream>>>(xn, WB + WB_QKV + (size_t)l*110592,
            BB + BB_QKV + l*576, qkv, 192, 576, 0);
        k_attn<<<N_*H_*5, 64, 0, stream>>>(qkv, ao);
        k_mgemm<<<dim3(ROWS_/64, 3), 256, 0, stream>>>(ao, WB + WB_OUT + (size_t)l*36864,
            BB + BB_OUT + l*192, nullptr, xf, xf, nullptr, nullptr, 192, 192, 2);
        k_ln<<<ROWS_/4, 256, 0, stream>>>(xf, ln2g, ln2b, (size_t)l*192, flag, xn, 0);
        k_mgemm128<<<dim3(ROWS_/128, 12), 256, 0, stream>>>(xn, WB + WB_FW1 + (size_t)l*147456,
            BB + BB_FW1 + l*768, hb, 192, 768, 1);
        k_mgemm<<<dim3(ROWS_/64, 3), 256, 0, stream>>>(hb, WB + WB_FW2 + (size_t)l*147456,
            BB + BB_FW2 + l*192, nullptr, xf, xf, nullptr, nullptr, 768, 192, 2);
        k_ln<<<ROWS_/4, 256, 0, stream>>>(xf, ng, nb, (size_t)l*192, flag, xn, 1);
        k_mgemm128<<<dim3(ROWS_/128, 36), 256, 0, stream>>>(xn, WB + WB_GAT + (size_t)l*442368,
            BB + BB_GAT + l*2304, xlr, 192, 2304, 4);
        k_alpha<<<G_*144/4, 256, 0, stream>>>((const _Float16*)xlr, lea, ea,
            (const _Float16*)(WB + WB_GWE) + (size_t)l*2304,
            (const _Float16*)(WB + WB_GATT) + (size_t)l*1152, flag, alp);
        k_segagg<<<G_*A_, 192, 0, stream>>>((const _Float16*)xlr, alp, gbias, (size_t)l*192, flag, xf);
    }
    k_store<<<(ROWS_*192+255)/256, 256, 0, stream>>>(xf, d_out, flag);
}